// Round 4
// baseline (608.487 us; speedup 1.0000x reference)
//
#include <hip/hip_runtime.h>
#include <stdint.h>

// ---------------------------------------------------------------------------
// TransformerXL encoder layer.  Inputs fp32, OUTPUT fp32 (ref returns f32).
// b=4 l=1024 d=512 h=8 dh=64.
// Pipeline: x->bf16, weights transpose+downcast -> qc/qr/k/v/rk proj GEMMs ->
// per-batch {content GEMM -> rel GEMM w/ shift-scatter epilogue -> softmax
// (P bf16 in-place over S) -> PV} -> o@Wo(x2) -> LN1 -> FFN1(relu) ->
// FFN2(x2) -> LN2 -> d_out (fp32).
// rel shift closed form: shifted[t,j] = R[t, 1024 + j - t],  R = (q+rb)@rk^T.
// GEMMs: bf16 MFMA 16x16x32, fp32 accum; logits/softmax/LN in fp32.
// ---------------------------------------------------------------------------

typedef unsigned short u16;
typedef __attribute__((ext_vector_type(8))) __bf16 bf16x8;
typedef __attribute__((ext_vector_type(8))) unsigned short u16x8;
typedef __attribute__((ext_vector_type(4))) float f32x4;
typedef __attribute__((ext_vector_type(4))) unsigned short u16x4;

#define BM 128
#define BN 128
#define BK 64

static __device__ __forceinline__ u16 f2bf(float f) {
  union { float f; unsigned int i; } v; v.f = f;
  unsigned int r = v.i + 0x7FFFu + ((v.i >> 16) & 1u);
  return (u16)(r >> 16);
}

enum { EPI_BF16 = 0, EPI_BF16_RELU = 1, EPI_BF16_DUAL = 2, EPI_F32 = 3,
       EPI_SHIFT_ADD = 4, EPI_F32_X2 = 5 };

// C[m,n] = sum_k A[m,k] * Bt[n,k]   (A: MxK row-major bf16, Bt: NxK row-major bf16)
// fragment layout (m89-verified): A/B lane: row/col = lane&15, k = (lane>>4)*8+e
//                                 C/D lane: col = lane&15, row = (lane>>4)*4+reg
template <int EPI>
__global__ __launch_bounds__(256) void gemm_bt(
    const u16* __restrict__ A, int64_t zA, int lda,
    const u16* __restrict__ Bt, int64_t zB, int ldb,
    char* __restrict__ Cb, int64_t zCbytes, int ldc,
    char* __restrict__ C2b,
    const float* __restrict__ bias1, const float* __restrict__ bias2,
    int M, int N, int K)
{
  __shared__ __align__(16) u16 As[BM * BK];
  __shared__ __align__(16) u16 Bs[BN * BK];

  const int z = blockIdx.z;
  A  += (int64_t)z * zA;
  Bt += (int64_t)z * zB;
  Cb += (int64_t)z * zCbytes;

  const int m0 = blockIdx.y * BM;
  const int n0 = blockIdx.x * BN;

  if (EPI == EPI_SHIFT_ADD) {
    // j = col - 1024 + row; skip tiles with no j in [0,1024)
    if (m0 + n0 + (BM - 1) + (BN - 1) < 1024) return;  // all j < 0
    if (m0 + n0 >= 1024 + 1024) return;                // all j >= 1024
  }

  const int tid  = threadIdx.x;
  const int lane = tid & 63;
  const int wid  = tid >> 6;
  const int wm = (wid >> 1) * 64;
  const int wn = (wid & 1) * 64;
  const int fr = lane & 15;
  const int fk = (lane >> 4) * 8;

  f32x4 acc[4][4];
#pragma unroll
  for (int m = 0; m < 4; ++m)
#pragma unroll
    for (int n = 0; n < 4; ++n) acc[m][n] = (f32x4){0.f, 0.f, 0.f, 0.f};

  for (int kt = 0; kt < K; kt += BK) {
    // register-staged global loads (issued before the barrier)
    u16x8 ra[4], rb[4];
#pragma unroll
    for (int it = 0; it < 4; ++it) {
      const int off = (it * 256 + tid) * 8;   // u16 offset into 128x64 tile
      const int r = off >> 6;                 // /BK
      const int c = off & (BK - 1);
      int gra = m0 + r; if (gra > M - 1) gra = M - 1;   // clamp (safety)
      int grb = n0 + r; if (grb > N - 1) grb = N - 1;   // clamp (PV has N=64)
      ra[it] = *(const u16x8*)(A  + (int64_t)gra * lda + kt + c);
      rb[it] = *(const u16x8*)(Bt + (int64_t)grb * ldb + kt + c);
    }
    __syncthreads();  // previous iteration's LDS reads complete
#pragma unroll
    for (int it = 0; it < 4; ++it) {
      const int off = (it * 256 + tid) * 8;
      *(u16x8*)&As[off] = ra[it];
      *(u16x8*)&Bs[off] = rb[it];
    }
    __syncthreads();  // staged tile visible

#pragma unroll
    for (int kk = 0; kk < BK; kk += 32) {
      bf16x8 af[4], bfv[4];
#pragma unroll
      for (int m = 0; m < 4; ++m)
        af[m] = *(const bf16x8*)&As[(wm + m * 16 + fr) * BK + kk + fk];
#pragma unroll
      for (int n = 0; n < 4; ++n)
        bfv[n] = *(const bf16x8*)&Bs[(wn + n * 16 + fr) * BK + kk + fk];
#pragma unroll
      for (int m = 0; m < 4; ++m)
#pragma unroll
        for (int n = 0; n < 4; ++n)
          acc[m][n] = __builtin_amdgcn_mfma_f32_16x16x32_bf16(af[m], bfv[n], acc[m][n], 0, 0, 0);
    }
  }

  // ---- epilogue ----
  const int r0 = m0 + wm + (lane >> 4) * 4;
  const int c0 = n0 + wn + fr;
#pragma unroll
  for (int m = 0; m < 4; ++m) {
#pragma unroll
    for (int n = 0; n < 4; ++n) {
      const int col = c0 + n * 16;
      if (col >= N) continue;   // PV: N=64
      float b1v = 0.f, b2v = 0.f;
      if (EPI == EPI_BF16 || EPI == EPI_BF16_RELU || EPI == EPI_F32_X2) {
        if (bias1) b1v = bias1[col];
      }
      if (EPI == EPI_BF16_DUAL) { b1v = bias1[col]; b2v = bias2[col]; }
#pragma unroll
      for (int j = 0; j < 4; ++j) {
        const int row = r0 + m * 16 + j;
        if (row >= M) continue;
        const float v = acc[m][n][j];
        if (EPI == EPI_BF16) {
          ((u16*)Cb)[(int64_t)row * ldc + col] = f2bf(v + b1v);
        } else if (EPI == EPI_BF16_RELU) {
          float t = v + b1v; t = t > 0.f ? t : 0.f;
          ((u16*)Cb)[(int64_t)row * ldc + col] = f2bf(t);
        } else if (EPI == EPI_BF16_DUAL) {
          ((u16*)Cb)[(int64_t)row * ldc + col]  = f2bf(v + b1v);
          ((u16*)C2b)[(int64_t)row * ldc + col] = f2bf(v + b2v);
        } else if (EPI == EPI_F32) {
          ((float*)Cb)[(int64_t)row * ldc + col] = v;
        } else if (EPI == EPI_F32_X2) {
          ((float*)Cb)[(int64_t)row * ldc + col] = 2.f * (v + b1v);
        } else if (EPI == EPI_SHIFT_ADD) {
          const int oc = col - 1024 + row;
          if (oc >= 0 && oc < 1024)
            ((float*)Cb)[(int64_t)row * ldc + oc] += v;
        }
      }
    }
  }
}

// fp32 elementwise downcast: out[i] = bf16(in[i]), 4 elems/thread
__global__ void convert_f32_bf16(const float* __restrict__ in, u16* __restrict__ out) {
  int idx = blockIdx.x * 256 + threadIdx.x;
  f32x4 v = ((const f32x4*)in)[idx];
  u16x4 o;
  o[0] = f2bf(v[0]); o[1] = f2bf(v[1]); o[2] = f2bf(v[2]); o[3] = f2bf(v[3]);
  ((u16x4*)out)[idx] = o;
}

// combined q biases; all inputs fp32
__global__ void prep_biases(const float* bq, const float* cb, const float* rb,
                            float* bqc, float* bqr)
{
  int i = blockIdx.x * 256 + threadIdx.x;
  if (i < 512) {
    bqc[i] = bq[i] + cb[i];
    bqr[i] = bq[i] + rb[i];
  }
}

// pe[i][j]: pos = i-1024; jf = j&255; inv = 10000^(-2*jf/512); sin | cos
__global__ void pe_kernel(u16* pe) {
  int idx = blockIdx.x * 256 + threadIdx.x;
  int i = idx >> 9, j = idx & 511, jf = j & 255;
  float inv = expf(-(float)jf * (2.0f / 512.0f) * 9.210340371976184f); // ln 1e4
  float arg = (float)(i - 1024) * inv;
  pe[idx] = f2bf((j < 256) ? sinf(arg) : cosf(arg));
}

// generic transpose + downcast: out[c][r] = bf16(in[r][c]); in R x C fp32
__global__ void transpose_f32_bf16(const float* __restrict__ in, int ldi,
                                   u16* __restrict__ out, int ldo, int R, int C) {
  __shared__ float t[32][33];
  int c0 = blockIdx.x * 32, r0 = blockIdx.y * 32;
  int x = threadIdx.x, y = threadIdx.y;   // block (32,8)
#pragma unroll
  for (int i = 0; i < 32; i += 8) {
    int r = r0 + y + i, c = c0 + x;
    if (r < R && c < C) t[y + i][x] = in[(int64_t)r * ldi + c];
  }
  __syncthreads();
#pragma unroll
  for (int i = 0; i < 32; i += 8) {
    int r = c0 + y + i, c = r0 + x;
    if (r < C && c < R) out[(int64_t)r * ldo + c] = f2bf(t[x][y + i]);
  }
}

// v (b,l,h,dh) bf16 -> vt (b,h,dh,l) bf16;  z = b*8+h
__global__ void transpose_v_kernel(const u16* __restrict__ v, u16* __restrict__ vt) {
  __shared__ u16 t[32][33];
  int z = blockIdx.z;
  const u16* in = v + (int64_t)(z >> 3) * 524288 + (z & 7) * 64;
  u16* out = vt + (int64_t)z * 65536;
  int c0 = blockIdx.x * 32, r0 = blockIdx.y * 32;
  int x = threadIdx.x, y = threadIdx.y;
#pragma unroll
  for (int i = 0; i < 32; i += 8)
    t[y + i][x] = in[(int64_t)(r0 + y + i) * 512 + c0 + x];
  __syncthreads();
#pragma unroll
  for (int i = 0; i < 32; i += 8)
    out[(int64_t)(c0 + y + i) * 1024 + r0 + x] = t[x][y + i];
}

// one block per row of S (1024 fp32); writes P (bf16) IN-PLACE over the row
// start.  All reads of the row happen before the first __syncthreads, writes
// after the second -> safe.  grid (1024, 8)
__global__ void softmax_kernel(float* __restrict__ S) {
  const int64_t row = (int64_t)blockIdx.y * 1024 + blockIdx.x;
  float* s = S + row * 1024;
  const int tid = threadIdx.x;
  f32x4 v = ((const f32x4*)s)[tid];
  float mx = fmaxf(fmaxf(v[0], v[1]), fmaxf(v[2], v[3]));
#pragma unroll
  for (int o = 32; o; o >>= 1) mx = fmaxf(mx, __shfl_xor(mx, o, 64));
  __shared__ float red[2][4];
  if ((tid & 63) == 0) red[0][tid >> 6] = mx;
  __syncthreads();
  mx = fmaxf(fmaxf(red[0][0], red[0][1]), fmaxf(red[0][2], red[0][3]));
  f32x4 e;
  e[0] = __expf(v[0] - mx); e[1] = __expf(v[1] - mx);
  e[2] = __expf(v[2] - mx); e[3] = __expf(v[3] - mx);
  float sm = e[0] + e[1] + e[2] + e[3];
#pragma unroll
  for (int o = 32; o; o >>= 1) sm += __shfl_xor(sm, o, 64);
  if ((tid & 63) == 0) red[1][tid >> 6] = sm;
  __syncthreads();
  sm = red[1][0] + red[1][1] + red[1][2] + red[1][3];
  float inv = 1.f / sm;
  u16x4 p;
  p[0] = f2bf(e[0] * inv); p[1] = f2bf(e[1] * inv);
  p[2] = f2bf(e[2] * inv); p[3] = f2bf(e[3] * inv);
  *(u16x4*)&((u16*)s)[tid * 4] = p;   // in-place: bf16 row over fp32 row start
}

// one wave per 512-elem row; 4 rows / 256-thread block.  grid(1024)
// OUT_F32: write fp32 (final output); else bf16 (feeds next GEMM).
template <int OUT_F32>
__global__ void layernorm_kernel(const float* __restrict__ X,
                                 const float* __restrict__ sc, const float* __restrict__ bi,
                                 void* __restrict__ outv) {
  const int row = blockIdx.x * 4 + (threadIdx.x >> 6);
  const int lane = threadIdx.x & 63;
  const float* x = X + (int64_t)row * 512;
  f32x4 a = ((const f32x4*)x)[lane];
  f32x4 b = ((const f32x4*)x)[lane + 64];
  float s = 0.f, q = 0.f;
#pragma unroll
  for (int e = 0; e < 4; ++e) { s += a[e] + b[e]; q += a[e]*a[e] + b[e]*b[e]; }
#pragma unroll
  for (int o = 32; o; o >>= 1) { s += __shfl_xor(s, o, 64); q += __shfl_xor(q, o, 64); }
  const float mu = s * (1.f / 512.f);
  const float var = q * (1.f / 512.f) - mu * mu;
  const float r = rsqrtf(var + 1e-6f);
  const int c1 = lane * 4, c2 = (lane + 64) * 4;
  f32x4 s1 = ((const f32x4*)sc)[lane],      s2 = ((const f32x4*)sc)[lane + 64];
  f32x4 g1 = ((const f32x4*)bi)[lane],      g2 = ((const f32x4*)bi)[lane + 64];
  if (OUT_F32) {
    float* out = (float*)outv;
    f32x4 o1, o2;
#pragma unroll
    for (int e = 0; e < 4; ++e) {
      o1[e] = (a[e] - mu) * r * s1[e] + g1[e];
      o2[e] = (b[e] - mu) * r * s2[e] + g2[e];
    }
    *(f32x4*)&out[(int64_t)row * 512 + c1] = o1;
    *(f32x4*)&out[(int64_t)row * 512 + c2] = o2;
  } else {
    u16* out = (u16*)outv;
    u16x4 o1, o2;
#pragma unroll
    for (int e = 0; e < 4; ++e) {
      o1[e] = f2bf((a[e] - mu) * r * s1[e] + g1[e]);
      o2[e] = f2bf((b[e] - mu) * r * s2[e] + g2[e]);
    }
    *(u16x4*)&out[(int64_t)row * 512 + c1] = o1;
    *(u16x4*)&out[(int64_t)row * 512 + c2] = o2;
  }
}

// ---------------------------------------------------------------------------
extern "C" void kernel_launch(void* const* d_in, const int* in_sizes, int n_in,
                              void* d_out, int out_size, void* d_ws, size_t ws_size,
                              hipStream_t stream) {
  const float* x    = (const float*)d_in[0];
  const float* Wq   = (const float*)d_in[1];
  const float* bq   = (const float*)d_in[2];
  const float* Wk   = (const float*)d_in[3];
  const float* bk   = (const float*)d_in[4];
  const float* Wv   = (const float*)d_in[5];
  const float* bv   = (const float*)d_in[6];
  const float* cb   = (const float*)d_in[7];
  const float* rb   = (const float*)d_in[8];
  const float* Wr   = (const float*)d_in[9];
  const float* Wo   = (const float*)d_in[10];
  const float* bo   = (const float*)d_in[11];
  const float* ln1s = (const float*)d_in[12];
  const float* ln1b = (const float*)d_in[13];
  const float* W1   = (const float*)d_in[14];
  const float* b1   = (const float*)d_in[15];
  const float* W2   = (const float*)d_in[16];
  const float* b2   = (const float*)d_in[17];
  const float* ln2s = (const float*)d_in[18];
  const float* ln2b = (const float*)d_in[19];
  (void)in_sizes; (void)n_in; (void)out_size; (void)ws_size;

  char* ws = (char*)d_ws;
  // ---- workspace layout (total ~70.5 MB) ----
  float* bqc = (float*)(ws + 0);          // 512 f32
  float* bqr = (float*)(ws + 2048);
  u16* pe  = (u16*)(ws + 20480);          // 2048x512 bf16 -> ends 2117632
  u16* WqT = (u16*)(ws + 2117632);        // 512x512 bf16 each
  u16* WkT = (u16*)(ws + 2641920);
  u16* WvT = (u16*)(ws + 3166208);
  u16* WoT = (u16*)(ws + 3690496);
  u16* WrT = (u16*)(ws + 4214784);
  u16* W1T = (u16*)(ws + 4739072);        // 2048x512
  u16* W2T = (u16*)(ws + 6836224);        // 512x2048
  u16* xb  = (u16*)(ws + 8933376);        // 4096x512 bf16 (x downcast)
  u16* qc  = (u16*)(ws + 13127680);       // 4096x512
  u16* qr  = (u16*)(ws + 17321984);
  u16* kb  = (u16*)(ws + 21516288);
  u16* vb  = (u16*)(ws + 25710592);
  u16* vt  = (u16*)(ws + 29904896);       // (b,h,dh,l)
  u16* rk  = (u16*)(ws + 34099200);       // 2048x512
  u16* ob  = (u16*)(ws + 36196352);       // 4096x512 (attn out)
  char* scratch = ws + 40390656;
  float* S  = (float*)scratch;                    // per-batch 8x1024x1024 fp32
  // post-attention reuse of the same scratch region:
  float* o2   = (float*)scratch;                  // 4096x512 fp32
  u16*   ln1  = (u16*)(scratch + 8388608);        // 4096x512 bf16
  u16*   ffn1 = (u16*)(scratch + 12582912);       // 4096x2048 bf16 (ends 29360128)
  float* f2   = o2;                               // o2 dead after LN1

  const dim3 blk(256), tb(32, 8);

  prep_biases<<<dim3(2), blk, 0, stream>>>(bq, cb, rb, bqc, bqr);
  pe_kernel<<<dim3(4096), blk, 0, stream>>>(pe);
  convert_f32_bf16<<<dim3(2048), blk, 0, stream>>>(x, xb);

  transpose_f32_bf16<<<dim3(16, 16), tb, 0, stream>>>(Wq, 512, WqT, 512, 512, 512);
  transpose_f32_bf16<<<dim3(16, 16), tb, 0, stream>>>(Wk, 512, WkT, 512, 512, 512);
  transpose_f32_bf16<<<dim3(16, 16), tb, 0, stream>>>(Wv, 512, WvT, 512, 512, 512);
  transpose_f32_bf16<<<dim3(16, 16), tb, 0, stream>>>(Wo, 512, WoT, 512, 512, 512);
  transpose_f32_bf16<<<dim3(16, 16), tb, 0, stream>>>(Wr, 512, WrT, 512, 512, 512);
  transpose_f32_bf16<<<dim3(64, 16), tb, 0, stream>>>(W1, 2048, W1T, 512, 512, 2048);
  transpose_f32_bf16<<<dim3(16, 64), tb, 0, stream>>>(W2, 512, W2T, 2048, 2048, 512);

  // projections (biases fp32 direct from d_in)
  gemm_bt<EPI_BF16_DUAL><<<dim3(4, 32, 1), blk, 0, stream>>>(
      xb, 0, 512, WqT, 0, 512, (char*)qc, 0, 512, (char*)qr, bqc, bqr, 4096, 512, 512);
  gemm_bt<EPI_BF16><<<dim3(4, 32, 1), blk, 0, stream>>>(
      xb, 0, 512, WkT, 0, 512, (char*)kb, 0, 512, nullptr, bk, nullptr, 4096, 512, 512);
  gemm_bt<EPI_BF16><<<dim3(4, 32, 1), blk, 0, stream>>>(
      xb, 0, 512, WvT, 0, 512, (char*)vb, 0, 512, nullptr, bv, nullptr, 4096, 512, 512);
  gemm_bt<EPI_BF16><<<dim3(4, 16, 1), blk, 0, stream>>>(
      pe, 0, 512, WrT, 0, 512, (char*)rk, 0, 512, nullptr, nullptr, nullptr, 2048, 512, 512);
  transpose_v_kernel<<<dim3(2, 32, 32), tb, 0, stream>>>(vb, vt);

  // attention, per batch; grid.z = head
  for (int b = 0; b < 4; ++b) {
    const u16* qcb = qc + (int64_t)b * 524288;
    const u16* qrb = qr + (int64_t)b * 524288;
    const u16* kbb = kb + (int64_t)b * 524288;
    // S[h,t,j] = qc . k
    gemm_bt<EPI_F32><<<dim3(8, 8, 8), blk, 0, stream>>>(
        qcb, 64, 512, kbb, 64, 512, (char*)S, 4194304, 1024, nullptr,
        nullptr, nullptr, 1024, 1024, 64);
    // S[h,t,j] += (qr . rk)[t, 1024+j-t]
    gemm_bt<EPI_SHIFT_ADD><<<dim3(16, 8, 8), blk, 0, stream>>>(
        qrb, 64, 512, rk, 64, 512, (char*)S, 4194304, 1024, nullptr,
        nullptr, nullptr, 1024, 2048, 64);
    softmax_kernel<<<dim3(1024, 8), blk, 0, stream>>>(S);
    // o[b,t,h*64+c] = P @ vt   (P = bf16 rows in-place over S, lda=2048)
    gemm_bt<EPI_BF16><<<dim3(1, 8, 8), blk, 0, stream>>>(
        (const u16*)S, 2097152, 2048, vt + (int64_t)b * 524288, 65536, 1024,
        (char*)(ob + (int64_t)b * 524288), 128, 512, nullptr,
        nullptr, nullptr, 1024, 64, 1024);
  }

  // o@Wo + bo, doubled -> fp32
  gemm_bt<EPI_F32_X2><<<dim3(4, 32, 1), blk, 0, stream>>>(
      ob, 0, 512, WoT, 0, 512, (char*)o2, 0, 512, nullptr, bo, nullptr, 4096, 512, 512);
  layernorm_kernel<0><<<dim3(1024), blk, 0, stream>>>(o2, ln1s, ln1b, ln1);
  // FFN
  gemm_bt<EPI_BF16_RELU><<<dim3(16, 32, 1), blk, 0, stream>>>(
      ln1, 0, 512, W1T, 0, 512, (char*)ffn1, 0, 2048, nullptr, b1, nullptr, 4096, 2048, 512);
  gemm_bt<EPI_F32_X2><<<dim3(4, 32, 1), blk, 0, stream>>>(
      ffn1, 0, 2048, W2T, 0, 2048, (char*)f2, 0, 512, nullptr, b2, nullptr, 4096, 512, 2048);
  layernorm_kernel<1><<<dim3(1024), blk, 0, stream>>>(f2, ln2s, ln2b, d_out);
}

// Round 5
// 271.031 us; speedup vs baseline: 2.2451x; 2.2451x over previous
//
#include <hip/hip_runtime.h>
#include <stdint.h>

// ---------------------------------------------------------------------------
// TransformerXL encoder layer.  Inputs fp32, OUTPUT fp32.  b=4 l=1024 d=512
// h=8 dh=64.
// Round 5: fused flash attention (content + relative-PE band + online softmax
// + PV in one kernel) replaces the S-matrix pipeline (was ~500us of 608us).
// rel shift closed form: shifted[t,j] = R[t, 1024 + j - t],  R = (q+rb)@rk^T.
// ---------------------------------------------------------------------------

typedef unsigned short u16;
typedef __attribute__((ext_vector_type(8))) __bf16 bf16x8;
typedef __attribute__((ext_vector_type(8))) unsigned short u16x8;
typedef __attribute__((ext_vector_type(4))) float f32x4;
typedef __attribute__((ext_vector_type(4))) unsigned short u16x4;

#define BM 128
#define BN 128
#define BK 64

static __device__ __forceinline__ u16 f2bf(float f) {
  union { float f; unsigned int i; } v; v.f = f;
  unsigned int r = v.i + 0x7FFFu + ((v.i >> 16) & 1u);
  return (u16)(r >> 16);
}

// swizzled u16 index into a [rows][64]-u16 LDS tile (16B chunk ^= row&7).
// kills the 16-way bank conflict of stride-128B column reads (G4 / T2).
static __device__ __forceinline__ int swzIdx(int r, int ch) {
  return (r << 6) + (((ch ^ (r & 7)) & 7) << 3);
}

// ---------------------------------------------------------------------------
// Fused attention.  grid (16 q-tiles, 8 heads, 4 batches), 256 threads.
// Block: 64 q-rows; wave w owns rows [w*16, w*16+16).  Loop over 16 kv-tiles
// of 64.  Per tile: content = qc@k^T (MFMA), rel band R[t,c] = qr[t].rk[u0w+c]
// (width 79 per wave), scatter-merge via wave-private LDS, online softmax,
// P(bf16)->LDS->PV MFMA.  No masking: u = 1024+j-t is always in [1,2047].
// ---------------------------------------------------------------------------
__global__ __launch_bounds__(256) void fused_attn_kernel(
    const u16* __restrict__ qc, const u16* __restrict__ qr,
    const u16* __restrict__ kb, const u16* __restrict__ vt,
    const u16* __restrict__ rk, u16* __restrict__ ob)
{
  __shared__ __align__(16) u16 kbLds[64 * 64];    // k tile  [j][d]
  __shared__ __align__(16) u16 vtLds[64 * 64];    // vt tile [c][j]
  __shared__ __align__(16) u16 rkLds[128 * 64];   // rk band [lr][d]
  __shared__ float rLds[4][16 * 84];              // per-wave R [ttw][c] (pad 84)
  __shared__ __align__(16) u16 pLds[4][16 * 64];  // per-wave P [ttw][j]

  const int tid  = threadIdx.x;
  const int lane = tid & 63;
  const int w    = tid >> 6;
  const int g    = lane >> 4;
  const int li   = lane & 15;
  const int t0   = blockIdx.x * 64;
  const int h    = blockIdx.y;
  const int b    = blockIdx.z;

  // A-frags: row = li (wave q-row), k = g*8 + kc*32  (m89 layout)
  const int64_t qoff = (int64_t)b * 524288 + (int64_t)(t0 + w * 16 + li) * 512
                     + h * 64 + g * 8;
  bf16x8 qcf[2], qrf[2];
  qcf[0] = *(const bf16x8*)(qc + qoff);
  qcf[1] = *(const bf16x8*)(qc + qoff + 32);
  qrf[0] = *(const bf16x8*)(qr + qoff);
  qrf[1] = *(const bf16x8*)(qr + qoff + 32);

  const u16* kbB = kb + (int64_t)b * 524288 + h * 64;   // row j: *512
  const u16* vtB = vt + (int64_t)(b * 8 + h) * 65536;   // row c: *1024
  const u16* rkB = rk + h * 64;                         // row u: *512

  float m_[4] = {-1e30f, -1e30f, -1e30f, -1e30f};
  float l_[4] = {0.f, 0.f, 0.f, 0.f};
  f32x4 o_[4];
#pragma unroll
  for (int n = 0; n < 4; ++n) o_[n] = (f32x4){0.f, 0.f, 0.f, 0.f};

  for (int it = 0; it < 16; ++it) {
    const int j0 = it * 64;
    const int ubase = 1024 + j0 - t0 - 63;   // always >= 1

    // ---- stage k / vt / rk band (reg -> swizzled LDS) ----
    u16x8 sk[2], svv[2], srr[4];
#pragma unroll
    for (int p = 0; p < 2; ++p) {
      const int flat = p * 256 + tid, r = flat >> 3, ch = flat & 7;
      sk[p]  = *(const u16x8*)(kbB + (int64_t)(j0 + r) * 512 + ch * 8);
      svv[p] = *(const u16x8*)(vtB + (int64_t)r * 1024 + j0 + ch * 8);
    }
#pragma unroll
    for (int p = 0; p < 4; ++p) {
      const int flat = p * 256 + tid, r = flat >> 3, ch = flat & 7;
      int u = ubase + r; u = u < 2047 ? u : 2047;   // pad row clamp
      srr[p] = *(const u16x8*)(rkB + (int64_t)u * 512 + ch * 8);
    }
    __syncthreads();   // prior iteration's LDS reads complete
#pragma unroll
    for (int p = 0; p < 2; ++p) {
      const int flat = p * 256 + tid, r = flat >> 3, ch = flat & 7;
      *(u16x8*)&kbLds[swzIdx(r, ch)] = sk[p];
      *(u16x8*)&vtLds[swzIdx(r, ch)] = svv[p];
    }
#pragma unroll
    for (int p = 0; p < 4; ++p) {
      const int flat = p * 256 + tid, r = flat >> 3, ch = flat & 7;
      *(u16x8*)&rkLds[swzIdx(r, ch)] = srr[p];
    }
    __syncthreads();

    // ---- content logits C[t, jj] ----
    f32x4 c_[4];
#pragma unroll
    for (int n = 0; n < 4; ++n) c_[n] = (f32x4){0.f, 0.f, 0.f, 0.f};
#pragma unroll
    for (int kc = 0; kc < 2; ++kc) {
      const int chn = kc * 4 + g;
#pragma unroll
      for (int n = 0; n < 4; ++n) {
        bf16x8 bb = *(const bf16x8*)&kbLds[swzIdx(n * 16 + li, chn)];
        c_[n] = __builtin_amdgcn_mfma_f32_16x16x32_bf16(qcf[kc], bb, c_[n], 0, 0, 0);
      }
    }
    // ---- rel band R[t, c] = qr[t] . rk[u0w + c],  c in [0,79) ----
    f32x4 r_[5];
#pragma unroll
    for (int f = 0; f < 5; ++f) r_[f] = (f32x4){0.f, 0.f, 0.f, 0.f};
#pragma unroll
    for (int kc = 0; kc < 2; ++kc) {
      const int chn = kc * 4 + g;
#pragma unroll
      for (int f = 0; f < 5; ++f) {
        const int lr = f * 16 + li + 48 - 16 * w;   // local band row, [0,128)
        bf16x8 bb = *(const bf16x8*)&rkLds[swzIdx(lr, chn)];
        r_[f] = __builtin_amdgcn_mfma_f32_16x16x32_bf16(qrf[kc], bb, r_[f], 0, 0, 0);
      }
    }
    // ---- R -> wave-private LDS, scatter-merge S = C + R[t, jj - ttw + 15] ----
    float* rwp = rLds[w];
#pragma unroll
    for (int f = 0; f < 5; ++f)
#pragma unroll
      for (int j = 0; j < 4; ++j)
        rwp[(g * 4 + j) * 84 + f * 16 + li] = r_[f][j];
    // (same-wave LDS dep: compiler inserts lgkmcnt wait)
    float sv2[4][4];
#pragma unroll
    for (int n = 0; n < 4; ++n)
#pragma unroll
      for (int j = 0; j < 4; ++j) {
        const int rw = g * 4 + j;
        sv2[n][j] = c_[n][j] + rwp[rw * 84 + (n * 16 + li - rw + 15)];
      }

    // ---- online softmax (row = g*4+j, spread over 16 lanes) ----
    float al[4], rs[4];
#pragma unroll
    for (int j = 0; j < 4; ++j) {
      float t = fmaxf(fmaxf(sv2[0][j], sv2[1][j]), fmaxf(sv2[2][j], sv2[3][j]));
#pragma unroll
      for (int off = 1; off < 16; off <<= 1) t = fmaxf(t, __shfl_xor(t, off, 64));
      const float nm = fmaxf(m_[j], t);
      al[j] = __expf(m_[j] - nm);
      m_[j] = nm;
      rs[j] = 0.f;
    }
    u16* pw = pLds[w];
#pragma unroll
    for (int n = 0; n < 4; ++n)
#pragma unroll
      for (int j = 0; j < 4; ++j) {
        const float p = __expf(sv2[n][j] - m_[j]);
        rs[j] += p;
        const int rw = g * 4 + j, col = n * 16 + li;
        pw[(rw << 6) + ((((col >> 3) ^ (rw & 7)) & 7) << 3) + (col & 7)] = f2bf(p);
      }
#pragma unroll
    for (int j = 0; j < 4; ++j) {
      float t = rs[j];
#pragma unroll
      for (int off = 1; off < 16; off <<= 1) t += __shfl_xor(t, off, 64);
      l_[j] = l_[j] * al[j] + t;
    }
#pragma unroll
    for (int n = 0; n < 4; ++n)
#pragma unroll
      for (int j = 0; j < 4; ++j) o_[n][j] *= al[j];

    // ---- PV: O[t, c] += P[t, jj] * vt[c, jj] ----
#pragma unroll
    for (int kc = 0; kc < 2; ++kc) {
      const int chn = kc * 4 + g;
      bf16x8 pa = *(const bf16x8*)&pw[swzIdx(li, chn)];
#pragma unroll
      for (int n = 0; n < 4; ++n) {
        bf16x8 vb = *(const bf16x8*)&vtLds[swzIdx(n * 16 + li, chn)];
        o_[n] = __builtin_amdgcn_mfma_f32_16x16x32_bf16(pa, vb, o_[n], 0, 0, 0);
      }
    }
  }

  // ---- epilogue: O /= l, write ob (bf16) ----
  float inv[4];
#pragma unroll
  for (int j = 0; j < 4; ++j) inv[j] = 1.f / l_[j];
  u16* obB = ob + (int64_t)b * 524288 + (int64_t)(t0 + w * 16) * 512 + h * 64;
#pragma unroll
  for (int n = 0; n < 4; ++n)
#pragma unroll
    for (int j = 0; j < 4; ++j)
      obB[(int64_t)(g * 4 + j) * 512 + n * 16 + li] = f2bf(o_[n][j] * inv[j]);
}

enum { EPI_BF16 = 0, EPI_BF16_RELU = 1, EPI_BF16_DUAL = 2, EPI_F32 = 3,
       EPI_F32_X2 = 5 };

// C[m,n] = sum_k A[m,k] * Bt[n,k]   (A: MxK row-major bf16, Bt: NxK row-major bf16)
template <int EPI>
__global__ __launch_bounds__(256) void gemm_bt(
    const u16* __restrict__ A, int64_t zA, int lda,
    const u16* __restrict__ Bt, int64_t zB, int ldb,
    char* __restrict__ Cb, int64_t zCbytes, int ldc,
    char* __restrict__ C2b,
    const float* __restrict__ bias1, const float* __restrict__ bias2,
    int M, int N, int K)
{
  __shared__ __align__(16) u16 As[BM * BK];
  __shared__ __align__(16) u16 Bs[BN * BK];

  const int z = blockIdx.z;
  A  += (int64_t)z * zA;
  Bt += (int64_t)z * zB;
  Cb += (int64_t)z * zCbytes;

  const int m0 = blockIdx.y * BM;
  const int n0 = blockIdx.x * BN;

  const int tid  = threadIdx.x;
  const int lane = tid & 63;
  const int wid  = tid >> 6;
  const int wm = (wid >> 1) * 64;
  const int wn = (wid & 1) * 64;
  const int fr = lane & 15;
  const int fk = (lane >> 4) * 8;

  f32x4 acc[4][4];
#pragma unroll
  for (int m = 0; m < 4; ++m)
#pragma unroll
    for (int n = 0; n < 4; ++n) acc[m][n] = (f32x4){0.f, 0.f, 0.f, 0.f};

  for (int kt = 0; kt < K; kt += BK) {
    u16x8 ra[4], rb[4];
#pragma unroll
    for (int it = 0; it < 4; ++it) {
      const int off = (it * 256 + tid) * 8;
      const int r = off >> 6;
      const int c = off & (BK - 1);
      int gra = m0 + r; if (gra > M - 1) gra = M - 1;
      int grb = n0 + r; if (grb > N - 1) grb = N - 1;
      ra[it] = *(const u16x8*)(A  + (int64_t)gra * lda + kt + c);
      rb[it] = *(const u16x8*)(Bt + (int64_t)grb * ldb + kt + c);
    }
    __syncthreads();
#pragma unroll
    for (int it = 0; it < 4; ++it) {
      const int off = (it * 256 + tid) * 8;
      *(u16x8*)&As[off] = ra[it];
      *(u16x8*)&Bs[off] = rb[it];
    }
    __syncthreads();

#pragma unroll
    for (int kk = 0; kk < BK; kk += 32) {
      bf16x8 af[4], bfv[4];
#pragma unroll
      for (int m = 0; m < 4; ++m)
        af[m] = *(const bf16x8*)&As[(wm + m * 16 + fr) * BK + kk + fk];
#pragma unroll
      for (int n = 0; n < 4; ++n)
        bfv[n] = *(const bf16x8*)&Bs[(wn + n * 16 + fr) * BK + kk + fk];
#pragma unroll
      for (int m = 0; m < 4; ++m)
#pragma unroll
        for (int n = 0; n < 4; ++n)
          acc[m][n] = __builtin_amdgcn_mfma_f32_16x16x32_bf16(af[m], bfv[n], acc[m][n], 0, 0, 0);
    }
  }

  const int r0 = m0 + wm + (lane >> 4) * 4;
  const int c0 = n0 + wn + fr;
#pragma unroll
  for (int m = 0; m < 4; ++m) {
#pragma unroll
    for (int n = 0; n < 4; ++n) {
      const int col = c0 + n * 16;
      if (col >= N) continue;
      float b1v = 0.f, b2v = 0.f;
      if (EPI == EPI_BF16 || EPI == EPI_BF16_RELU || EPI == EPI_F32_X2) {
        if (bias1) b1v = bias1[col];
      }
      if (EPI == EPI_BF16_DUAL) { b1v = bias1[col]; b2v = bias2[col]; }
#pragma unroll
      for (int j = 0; j < 4; ++j) {
        const int row = r0 + m * 16 + j;
        if (row >= M) continue;
        const float v = acc[m][n][j];
        if (EPI == EPI_BF16) {
          ((u16*)Cb)[(int64_t)row * ldc + col] = f2bf(v + b1v);
        } else if (EPI == EPI_BF16_RELU) {
          float t = v + b1v; t = t > 0.f ? t : 0.f;
          ((u16*)Cb)[(int64_t)row * ldc + col] = f2bf(t);
        } else if (EPI == EPI_BF16_DUAL) {
          ((u16*)Cb)[(int64_t)row * ldc + col]  = f2bf(v + b1v);
          ((u16*)C2b)[(int64_t)row * ldc + col] = f2bf(v + b2v);
        } else if (EPI == EPI_F32) {
          ((float*)Cb)[(int64_t)row * ldc + col] = v;
        } else if (EPI == EPI_F32_X2) {
          ((float*)Cb)[(int64_t)row * ldc + col] = 2.f * (v + b1v);
        }
      }
    }
  }
}

__global__ void convert_f32_bf16(const float* __restrict__ in, u16* __restrict__ out) {
  int idx = blockIdx.x * 256 + threadIdx.x;
  f32x4 v = ((const f32x4*)in)[idx];
  u16x4 o;
  o[0] = f2bf(v[0]); o[1] = f2bf(v[1]); o[2] = f2bf(v[2]); o[3] = f2bf(v[3]);
  ((u16x4*)out)[idx] = o;
}

__global__ void prep_biases(const float* bq, const float* cb, const float* rb,
                            float* bqc, float* bqr)
{
  int i = blockIdx.x * 256 + threadIdx.x;
  if (i < 512) {
    bqc[i] = bq[i] + cb[i];
    bqr[i] = bq[i] + rb[i];
  }
}

// pe[i][j]: pos = i-1024; jf = j&255; inv = 10000^(-2*jf/512); sin | cos
__global__ void pe_kernel(u16* pe) {
  int idx = blockIdx.x * 256 + threadIdx.x;
  int i = idx >> 9, j = idx & 511, jf = j & 255;
  float inv = expf(-(float)jf * (2.0f / 512.0f) * 9.210340371976184f); // ln 1e4
  float arg = (float)(i - 1024) * inv;
  pe[idx] = f2bf((j < 256) ? sinf(arg) : cosf(arg));
}

__global__ void transpose_f32_bf16(const float* __restrict__ in, int ldi,
                                   u16* __restrict__ out, int ldo, int R, int C) {
  __shared__ float t[32][33];
  int c0 = blockIdx.x * 32, r0 = blockIdx.y * 32;
  int x = threadIdx.x, y = threadIdx.y;   // block (32,8)
#pragma unroll
  for (int i = 0; i < 32; i += 8) {
    int r = r0 + y + i, c = c0 + x;
    if (r < R && c < C) t[y + i][x] = in[(int64_t)r * ldi + c];
  }
  __syncthreads();
#pragma unroll
  for (int i = 0; i < 32; i += 8) {
    int r = c0 + y + i, c = r0 + x;
    if (r < C && c < R) out[(int64_t)r * ldo + c] = f2bf(t[x][y + i]);
  }
}

// v (b,l,h,dh) bf16 -> vt (b,h,dh,l) bf16;  z = b*8+h
__global__ void transpose_v_kernel(const u16* __restrict__ v, u16* __restrict__ vt) {
  __shared__ u16 t[32][33];
  int z = blockIdx.z;
  const u16* in = v + (int64_t)(z >> 3) * 524288 + (z & 7) * 64;
  u16* out = vt + (int64_t)z * 65536;
  int c0 = blockIdx.x * 32, r0 = blockIdx.y * 32;
  int x = threadIdx.x, y = threadIdx.y;
#pragma unroll
  for (int i = 0; i < 32; i += 8)
    t[y + i][x] = in[(int64_t)(r0 + y + i) * 512 + c0 + x];
  __syncthreads();
#pragma unroll
  for (int i = 0; i < 32; i += 8)
    out[(int64_t)(c0 + y + i) * 1024 + r0 + x] = t[x][y + i];
}

// one wave per 512-elem row; 4 rows / 256-thread block.  grid(1024)
template <int OUT_F32>
__global__ void layernorm_kernel(const float* __restrict__ X,
                                 const float* __restrict__ sc, const float* __restrict__ bi,
                                 void* __restrict__ outv) {
  const int row = blockIdx.x * 4 + (threadIdx.x >> 6);
  const int lane = threadIdx.x & 63;
  const float* x = X + (int64_t)row * 512;
  f32x4 a = ((const f32x4*)x)[lane];
  f32x4 b = ((const f32x4*)x)[lane + 64];
  float s = 0.f, q = 0.f;
#pragma unroll
  for (int e = 0; e < 4; ++e) { s += a[e] + b[e]; q += a[e]*a[e] + b[e]*b[e]; }
#pragma unroll
  for (int o = 32; o; o >>= 1) { s += __shfl_xor(s, o, 64); q += __shfl_xor(q, o, 64); }
  const float mu = s * (1.f / 512.f);
  const float var = q * (1.f / 512.f) - mu * mu;
  const float r = rsqrtf(var + 1e-6f);
  const int c1 = lane * 4, c2 = (lane + 64) * 4;
  f32x4 s1 = ((const f32x4*)sc)[lane],      s2 = ((const f32x4*)sc)[lane + 64];
  f32x4 g1 = ((const f32x4*)bi)[lane],      g2 = ((const f32x4*)bi)[lane + 64];
  if (OUT_F32) {
    float* out = (float*)outv;
    f32x4 o1, o2;
#pragma unroll
    for (int e = 0; e < 4; ++e) {
      o1[e] = (a[e] - mu) * r * s1[e] + g1[e];
      o2[e] = (b[e] - mu) * r * s2[e] + g2[e];
    }
    *(f32x4*)&out[(int64_t)row * 512 + c1] = o1;
    *(f32x4*)&out[(int64_t)row * 512 + c2] = o2;
  } else {
    u16* out = (u16*)outv;
    u16x4 o1, o2;
#pragma unroll
    for (int e = 0; e < 4; ++e) {
      o1[e] = f2bf((a[e] - mu) * r * s1[e] + g1[e]);
      o2[e] = f2bf((b[e] - mu) * r * s2[e] + g2[e]);
    }
    *(u16x4*)&out[(int64_t)row * 512 + c1] = o1;
    *(u16x4*)&out[(int64_t)row * 512 + c2] = o2;
  }
}

// ---------------------------------------------------------------------------
extern "C" void kernel_launch(void* const* d_in, const int* in_sizes, int n_in,
                              void* d_out, int out_size, void* d_ws, size_t ws_size,
                              hipStream_t stream) {
  const float* x    = (const float*)d_in[0];
  const float* Wq   = (const float*)d_in[1];
  const float* bq   = (const float*)d_in[2];
  const float* Wk   = (const float*)d_in[3];
  const float* bk   = (const float*)d_in[4];
  const float* Wv   = (const float*)d_in[5];
  const float* bv   = (const float*)d_in[6];
  const float* cb   = (const float*)d_in[7];
  const float* rb   = (const float*)d_in[8];
  const float* Wr   = (const float*)d_in[9];
  const float* Wo   = (const float*)d_in[10];
  const float* bo   = (const float*)d_in[11];
  const float* ln1s = (const float*)d_in[12];
  const float* ln1b = (const float*)d_in[13];
  const float* W1   = (const float*)d_in[14];
  const float* b1   = (const float*)d_in[15];
  const float* W2   = (const float*)d_in[16];
  const float* b2   = (const float*)d_in[17];
  const float* ln2s = (const float*)d_in[18];
  const float* ln2b = (const float*)d_in[19];
  (void)in_sizes; (void)n_in; (void)out_size; (void)ws_size;

  char* ws = (char*)d_ws;
  float* bqc = (float*)(ws + 0);          // 512 f32
  float* bqr = (float*)(ws + 2048);
  u16* pe  = (u16*)(ws + 20480);          // 2048x512 bf16
  u16* WqT = (u16*)(ws + 2117632);        // 512x512 bf16 each
  u16* WkT = (u16*)(ws + 2641920);
  u16* WvT = (u16*)(ws + 3166208);
  u16* WoT = (u16*)(ws + 3690496);
  u16* WrT = (u16*)(ws + 4214784);
  u16* W1T = (u16*)(ws + 4739072);        // 2048x512
  u16* W2T = (u16*)(ws + 6836224);        // 512x2048
  u16* xb  = (u16*)(ws + 8933376);        // 4096x512 bf16
  u16* qc  = (u16*)(ws + 13127680);       // 4096x512
  u16* qr  = (u16*)(ws + 17321984);
  u16* kb  = (u16*)(ws + 21516288);
  u16* vb  = (u16*)(ws + 25710592);
  u16* vt  = (u16*)(ws + 29904896);       // (b,h,dh,l)
  u16* rk  = (u16*)(ws + 34099200);       // 2048x512
  u16* ob  = (u16*)(ws + 36196352);       // 4096x512 (attn out)
  char* scratch = ws + 40390656;
  float* o2   = (float*)scratch;                  // 4096x512 fp32
  u16*   ln1  = (u16*)(scratch + 8388608);        // 4096x512 bf16
  u16*   ffn1 = (u16*)(scratch + 12582912);       // 4096x2048 bf16
  float* f2   = o2;                               // o2 dead after LN1

  const dim3 blk(256), tb(32, 8);

  prep_biases<<<dim3(2), blk, 0, stream>>>(bq, cb, rb, bqc, bqr);
  pe_kernel<<<dim3(4096), blk, 0, stream>>>(pe);
  convert_f32_bf16<<<dim3(2048), blk, 0, stream>>>(x, xb);

  transpose_f32_bf16<<<dim3(16, 16), tb, 0, stream>>>(Wq, 512, WqT, 512, 512, 512);
  transpose_f32_bf16<<<dim3(16, 16), tb, 0, stream>>>(Wk, 512, WkT, 512, 512, 512);
  transpose_f32_bf16<<<dim3(16, 16), tb, 0, stream>>>(Wv, 512, WvT, 512, 512, 512);
  transpose_f32_bf16<<<dim3(16, 16), tb, 0, stream>>>(Wo, 512, WoT, 512, 512, 512);
  transpose_f32_bf16<<<dim3(16, 16), tb, 0, stream>>>(Wr, 512, WrT, 512, 512, 512);
  transpose_f32_bf16<<<dim3(64, 16), tb, 0, stream>>>(W1, 2048, W1T, 512, 512, 2048);
  transpose_f32_bf16<<<dim3(16, 64), tb, 0, stream>>>(W2, 512, W2T, 2048, 2048, 512);

  // projections
  gemm_bt<EPI_BF16_DUAL><<<dim3(4, 32, 1), blk, 0, stream>>>(
      xb, 0, 512, WqT, 0, 512, (char*)qc, 0, 512, (char*)qr, bqc, bqr, 4096, 512, 512);
  gemm_bt<EPI_BF16><<<dim3(4, 32, 1), blk, 0, stream>>>(
      xb, 0, 512, WkT, 0, 512, (char*)kb, 0, 512, nullptr, bk, nullptr, 4096, 512, 512);
  gemm_bt<EPI_BF16><<<dim3(4, 32, 1), blk, 0, stream>>>(
      xb, 0, 512, WvT, 0, 512, (char*)vb, 0, 512, nullptr, bv, nullptr, 4096, 512, 512);
  gemm_bt<EPI_BF16><<<dim3(4, 16, 1), blk, 0, stream>>>(
      pe, 0, 512, WrT, 0, 512, (char*)rk, 0, 512, nullptr, nullptr, nullptr, 2048, 512, 512);
  transpose_v_kernel<<<dim3(2, 32, 32), tb, 0, stream>>>(vb, vt);

  // fused attention (replaces content/shift/softmax/PV pipeline)
  fused_attn_kernel<<<dim3(16, 8, 4), blk, 0, stream>>>(qc, qr, kb, vt, rk, ob);

  // o@Wo + bo, doubled -> fp32
  gemm_bt<EPI_F32_X2><<<dim3(4, 32, 1), blk, 0, stream>>>(
      ob, 0, 512, WoT, 0, 512, (char*)o2, 0, 512, nullptr, bo, nullptr, 4096, 512, 512);
  layernorm_kernel<0><<<dim3(1024), blk, 0, stream>>>(o2, ln1s, ln1b, ln1);
  // FFN
  gemm_bt<EPI_BF16_RELU><<<dim3(16, 32, 1), blk, 0, stream>>>(
      ln1, 0, 512, W1T, 0, 512, (char*)ffn1, 0, 2048, nullptr, b1, nullptr, 4096, 2048, 512);
  gemm_bt<EPI_F32_X2><<<dim3(4, 32, 1), blk, 0, stream>>>(
      ffn1, 0, 2048, W2T, 0, 2048, (char*)f2, 0, 512, nullptr, b2, nullptr, 4096, 512, 2048);
  layernorm_kernel<1><<<dim3(1024), blk, 0, stream>>>(f2, ln2s, ln2b, d_out);
}

// Round 6
// 205.140 us; speedup vs baseline: 2.9662x; 1.3212x over previous
//
#include <hip/hip_runtime.h>
#include <stdint.h>

// ---------------------------------------------------------------------------
// TransformerXL encoder layer.  Inputs fp32, OUTPUT fp32.  b=4 l=1024 d=512
// h=8 dh=64.
// Round 6: GEMM tail attack.  (1) global_load_lds width-16 staging (m97
// pattern; round-1 NaN proven unrelated), (2) BN=64 tile variant so N=512
// GEMMs launch 256 blocks (was 128 = half the CUs idle), (3) all 7 weight
// transposes -> 1 dispatch, k/v projections z-batched.  fused_attn unchanged.
// rel shift closed form: shifted[t,j] = R[t, 1024 + j - t],  R = (q+rb)@rk^T.
// ---------------------------------------------------------------------------

typedef unsigned short u16;
typedef __attribute__((ext_vector_type(8))) __bf16 bf16x8;
typedef __attribute__((ext_vector_type(8))) unsigned short u16x8;
typedef __attribute__((ext_vector_type(4))) float f32x4;
typedef __attribute__((ext_vector_type(4))) unsigned short u16x4;

#define BK 64

static __device__ __forceinline__ u16 f2bf(float f) {
  union { float f; unsigned int i; } v; v.f = f;
  unsigned int r = v.i + 0x7FFFu + ((v.i >> 16) & 1u);
  return (u16)(r >> 16);
}

// global->LDS direct copy, 16B per lane (lds dest must be linear in lane id).
static __device__ __forceinline__ void gld16(const void* g, void* l) {
  __builtin_amdgcn_global_load_lds(
      (__attribute__((address_space(1))) void*)(uintptr_t)g,
      (__attribute__((address_space(3))) void*)(uintptr_t)l,
      16, 0, 0);
}

// swizzled u16 index into a [rows][64]-u16 LDS tile (16B chunk ^= row&7).
static __device__ __forceinline__ int swzIdx(int r, int ch) {
  return (r << 6) + (((ch ^ (r & 7)) & 7) << 3);
}

// ---------------------------------------------------------------------------
// Fused attention (unchanged from round 5).  grid (16 q-tiles, 8 heads, 4 b).
// ---------------------------------------------------------------------------
__global__ __launch_bounds__(256) void fused_attn_kernel(
    const u16* __restrict__ qc, const u16* __restrict__ qr,
    const u16* __restrict__ kb, const u16* __restrict__ vt,
    const u16* __restrict__ rk, u16* __restrict__ ob)
{
  __shared__ __align__(16) u16 kbLds[64 * 64];    // k tile  [j][d]
  __shared__ __align__(16) u16 vtLds[64 * 64];    // vt tile [c][j]
  __shared__ __align__(16) u16 rkLds[128 * 64];   // rk band [lr][d]
  __shared__ float rLds[4][16 * 84];              // per-wave R [ttw][c] (pad 84)
  __shared__ __align__(16) u16 pLds[4][16 * 64];  // per-wave P [ttw][j]

  const int tid  = threadIdx.x;
  const int lane = tid & 63;
  const int w    = tid >> 6;
  const int g    = lane >> 4;
  const int li   = lane & 15;
  const int t0   = blockIdx.x * 64;
  const int h    = blockIdx.y;
  const int b    = blockIdx.z;

  const int64_t qoff = (int64_t)b * 524288 + (int64_t)(t0 + w * 16 + li) * 512
                     + h * 64 + g * 8;
  bf16x8 qcf[2], qrf[2];
  qcf[0] = *(const bf16x8*)(qc + qoff);
  qcf[1] = *(const bf16x8*)(qc + qoff + 32);
  qrf[0] = *(const bf16x8*)(qr + qoff);
  qrf[1] = *(const bf16x8*)(qr + qoff + 32);

  const u16* kbB = kb + (int64_t)b * 524288 + h * 64;
  const u16* vtB = vt + (int64_t)(b * 8 + h) * 65536;
  const u16* rkB = rk + h * 64;

  float m_[4] = {-1e30f, -1e30f, -1e30f, -1e30f};
  float l_[4] = {0.f, 0.f, 0.f, 0.f};
  f32x4 o_[4];
#pragma unroll
  for (int n = 0; n < 4; ++n) o_[n] = (f32x4){0.f, 0.f, 0.f, 0.f};

  for (int it = 0; it < 16; ++it) {
    const int j0 = it * 64;
    const int ubase = 1024 + j0 - t0 - 63;

    u16x8 sk[2], svv[2], srr[4];
#pragma unroll
    for (int p = 0; p < 2; ++p) {
      const int flat = p * 256 + tid, r = flat >> 3, ch = flat & 7;
      sk[p]  = *(const u16x8*)(kbB + (int64_t)(j0 + r) * 512 + ch * 8);
      svv[p] = *(const u16x8*)(vtB + (int64_t)r * 1024 + j0 + ch * 8);
    }
#pragma unroll
    for (int p = 0; p < 4; ++p) {
      const int flat = p * 256 + tid, r = flat >> 3, ch = flat & 7;
      int u = ubase + r; u = u < 2047 ? u : 2047;
      srr[p] = *(const u16x8*)(rkB + (int64_t)u * 512 + ch * 8);
    }
    __syncthreads();
#pragma unroll
    for (int p = 0; p < 2; ++p) {
      const int flat = p * 256 + tid, r = flat >> 3, ch = flat & 7;
      *(u16x8*)&kbLds[swzIdx(r, ch)] = sk[p];
      *(u16x8*)&vtLds[swzIdx(r, ch)] = svv[p];
    }
#pragma unroll
    for (int p = 0; p < 4; ++p) {
      const int flat = p * 256 + tid, r = flat >> 3, ch = flat & 7;
      *(u16x8*)&rkLds[swzIdx(r, ch)] = srr[p];
    }
    __syncthreads();

    f32x4 c_[4];
#pragma unroll
    for (int n = 0; n < 4; ++n) c_[n] = (f32x4){0.f, 0.f, 0.f, 0.f};
#pragma unroll
    for (int kc = 0; kc < 2; ++kc) {
      const int chn = kc * 4 + g;
#pragma unroll
      for (int n = 0; n < 4; ++n) {
        bf16x8 bb = *(const bf16x8*)&kbLds[swzIdx(n * 16 + li, chn)];
        c_[n] = __builtin_amdgcn_mfma_f32_16x16x32_bf16(qcf[kc], bb, c_[n], 0, 0, 0);
      }
    }
    f32x4 r_[5];
#pragma unroll
    for (int f = 0; f < 5; ++f) r_[f] = (f32x4){0.f, 0.f, 0.f, 0.f};
#pragma unroll
    for (int kc = 0; kc < 2; ++kc) {
      const int chn = kc * 4 + g;
#pragma unroll
      for (int f = 0; f < 5; ++f) {
        const int lr = f * 16 + li + 48 - 16 * w;
        bf16x8 bb = *(const bf16x8*)&rkLds[swzIdx(lr, chn)];
        r_[f] = __builtin_amdgcn_mfma_f32_16x16x32_bf16(qrf[kc], bb, r_[f], 0, 0, 0);
      }
    }
    float* rwp = rLds[w];
#pragma unroll
    for (int f = 0; f < 5; ++f)
#pragma unroll
      for (int j = 0; j < 4; ++j)
        rwp[(g * 4 + j) * 84 + f * 16 + li] = r_[f][j];
    float sv2[4][4];
#pragma unroll
    for (int n = 0; n < 4; ++n)
#pragma unroll
      for (int j = 0; j < 4; ++j) {
        const int rw = g * 4 + j;
        sv2[n][j] = c_[n][j] + rwp[rw * 84 + (n * 16 + li - rw + 15)];
      }

    float al[4], rs[4];
#pragma unroll
    for (int j = 0; j < 4; ++j) {
      float t = fmaxf(fmaxf(sv2[0][j], sv2[1][j]), fmaxf(sv2[2][j], sv2[3][j]));
#pragma unroll
      for (int off = 1; off < 16; off <<= 1) t = fmaxf(t, __shfl_xor(t, off, 64));
      const float nm = fmaxf(m_[j], t);
      al[j] = __expf(m_[j] - nm);
      m_[j] = nm;
      rs[j] = 0.f;
    }
    u16* pw = pLds[w];
#pragma unroll
    for (int n = 0; n < 4; ++n)
#pragma unroll
      for (int j = 0; j < 4; ++j) {
        const float p = __expf(sv2[n][j] - m_[j]);
        rs[j] += p;
        const int rw = g * 4 + j, col = n * 16 + li;
        pw[(rw << 6) + ((((col >> 3) ^ (rw & 7)) & 7) << 3) + (col & 7)] = f2bf(p);
      }
#pragma unroll
    for (int j = 0; j < 4; ++j) {
      float t = rs[j];
#pragma unroll
      for (int off = 1; off < 16; off <<= 1) t += __shfl_xor(t, off, 64);
      l_[j] = l_[j] * al[j] + t;
    }
#pragma unroll
    for (int n = 0; n < 4; ++n)
#pragma unroll
      for (int j = 0; j < 4; ++j) o_[n][j] *= al[j];

#pragma unroll
    for (int kc = 0; kc < 2; ++kc) {
      const int chn = kc * 4 + g;
      bf16x8 pa = *(const bf16x8*)&pw[swzIdx(li, chn)];
#pragma unroll
      for (int n = 0; n < 4; ++n) {
        bf16x8 vb = *(const bf16x8*)&vtLds[swzIdx(n * 16 + li, chn)];
        o_[n] = __builtin_amdgcn_mfma_f32_16x16x32_bf16(pa, vb, o_[n], 0, 0, 0);
      }
    }
  }

  float inv[4];
#pragma unroll
  for (int j = 0; j < 4; ++j) inv[j] = 1.f / l_[j];
  u16* obB = ob + (int64_t)b * 524288 + (int64_t)(t0 + w * 16) * 512 + h * 64;
#pragma unroll
  for (int n = 0; n < 4; ++n)
#pragma unroll
    for (int j = 0; j < 4; ++j)
      obB[(int64_t)(g * 4 + j) * 512 + n * 16 + li] = f2bf(o_[n][j] * inv[j]);
}

enum { EPI_BF16 = 0, EPI_BF16_RELU = 1, EPI_BF16_DUAL = 2, EPI_F32_X2 = 5 };

// C[m,n] = sum_k A[m,k] * Bt[n,k].  Tile 128 x (NW*32): 4 waves (2M x 2N),
// per-wave 64 x (NW*16), acc[4][NW].  global_load_lds width-16 staging.
template <int EPI, int NW>
__global__ __launch_bounds__(256) void gemm_bt(
    const u16* __restrict__ A, int64_t zA, int lda,
    const u16* __restrict__ Bt, int64_t zB, int ldb,
    char* __restrict__ Cb, int64_t zCbytes, int ldc,
    char* __restrict__ C2b,
    const float* __restrict__ bias1, int zbias,
    const float* __restrict__ bias2,
    int M, int N, int K)
{
  __shared__ __align__(16) u16 As[128 * BK];
  __shared__ __align__(16) u16 Bs[NW * 32 * BK];

  const int z = blockIdx.z;
  A  += (int64_t)z * zA;
  Bt += (int64_t)z * zB;
  Cb += (int64_t)z * zCbytes;

  const int m0 = blockIdx.y * 128;
  const int n0 = blockIdx.x * (NW * 32);

  const int tid  = threadIdx.x;
  const int lane = tid & 63;
  const int wid  = tid >> 6;
  const int wm = (wid >> 1) * 64;
  const int wn = (wid & 1) * (NW * 16);
  const int fr = lane & 15;
  const int fk = (lane >> 4) * 8;

  f32x4 acc[4][NW];
#pragma unroll
  for (int m = 0; m < 4; ++m)
#pragma unroll
    for (int n = 0; n < NW; ++n) acc[m][n] = (f32x4){0.f, 0.f, 0.f, 0.f};

  for (int kt = 0; kt < K; kt += BK) {
    __syncthreads();   // previous iteration's LDS reads complete
#pragma unroll
    for (int it = 0; it < 4; ++it) {
      const int off = (it * 256 + tid) * 8;
      const int r = off >> 6, c = off & (BK - 1);
      int gr = m0 + r; if (gr > M - 1) gr = M - 1;
      gld16(A + (int64_t)gr * lda + kt + c, &As[off]);
    }
#pragma unroll
    for (int it = 0; it < NW; ++it) {
      const int off = (it * 256 + tid) * 8;
      const int r = off >> 6, c = off & (BK - 1);
      int gr = n0 + r; if (gr > N - 1) gr = N - 1;
      gld16(Bt + (int64_t)gr * ldb + kt + c, &Bs[off]);
    }
    __syncthreads();   // barrier drains vmcnt -> staged tile visible

#pragma unroll
    for (int kk = 0; kk < BK; kk += 32) {
      bf16x8 af[4], bfv[NW];
#pragma unroll
      for (int m = 0; m < 4; ++m)
        af[m] = *(const bf16x8*)&As[(wm + m * 16 + fr) * BK + kk + fk];
#pragma unroll
      for (int n = 0; n < NW; ++n)
        bfv[n] = *(const bf16x8*)&Bs[(wn + n * 16 + fr) * BK + kk + fk];
#pragma unroll
      for (int m = 0; m < 4; ++m)
#pragma unroll
        for (int n = 0; n < NW; ++n)
          acc[m][n] = __builtin_amdgcn_mfma_f32_16x16x32_bf16(af[m], bfv[n], acc[m][n], 0, 0, 0);
    }
  }

  const int r0 = m0 + wm + (lane >> 4) * 4;
  const int c0 = n0 + wn + fr;
#pragma unroll
  for (int m = 0; m < 4; ++m) {
#pragma unroll
    for (int n = 0; n < NW; ++n) {
      const int col = c0 + n * 16;
      if (col >= N) continue;
      float b1v = 0.f, b2v = 0.f;
      if (EPI == EPI_BF16 || EPI == EPI_BF16_RELU || EPI == EPI_F32_X2) {
        if (bias1) b1v = bias1[z * zbias + col];
      }
      if (EPI == EPI_BF16_DUAL) { b1v = bias1[col]; b2v = bias2[col]; }
#pragma unroll
      for (int j = 0; j < 4; ++j) {
        const int row = r0 + m * 16 + j;
        if (row >= M) continue;
        const float v = acc[m][n][j];
        if (EPI == EPI_BF16) {
          ((u16*)Cb)[(int64_t)row * ldc + col] = f2bf(v + b1v);
        } else if (EPI == EPI_BF16_RELU) {
          float t = v + b1v; t = t > 0.f ? t : 0.f;
          ((u16*)Cb)[(int64_t)row * ldc + col] = f2bf(t);
        } else if (EPI == EPI_BF16_DUAL) {
          ((u16*)Cb)[(int64_t)row * ldc + col]  = f2bf(v + b1v);
          ((u16*)C2b)[(int64_t)row * ldc + col] = f2bf(v + b2v);
        } else if (EPI == EPI_F32_X2) {
          ((float*)Cb)[(int64_t)row * ldc + col] = 2.f * (v + b1v);
        }
      }
    }
  }
}

__global__ void convert_f32_bf16(const float* __restrict__ in, u16* __restrict__ out) {
  int idx = blockIdx.x * 256 + threadIdx.x;
  f32x4 v = ((const f32x4*)in)[idx];
  u16x4 o;
  o[0] = f2bf(v[0]); o[1] = f2bf(v[1]); o[2] = f2bf(v[2]); o[3] = f2bf(v[3]);
  ((u16x4*)out)[idx] = o;
}

// combined q biases + packed k/v biases
__global__ void prep_biases(const float* bq, const float* cb, const float* rb,
                            const float* bk, const float* bv,
                            float* bqc, float* bqr, float* bkv)
{
  int i = blockIdx.x * 256 + threadIdx.x;
  if (i < 512) {
    bqc[i] = bq[i] + cb[i];
    bqr[i] = bq[i] + rb[i];
    bkv[i] = bk[i];
    bkv[512 + i] = bv[i];
  }
}

// pe[i][j]: pos = i-1024; jf = j&255; inv = 10000^(-2*jf/512); sin | cos
__global__ void pe_kernel(u16* pe) {
  int idx = blockIdx.x * 256 + threadIdx.x;
  int i = idx >> 9, j = idx & 511, jf = j & 255;
  float inv = expf(-(float)jf * (2.0f / 512.0f) * 9.210340371976184f); // ln 1e4
  float arg = (float)(i - 1024) * inv;
  pe[idx] = f2bf((j < 256) ? sinf(arg) : cosf(arg));
}

// ALL weight transposes in one dispatch.  32x32 tiles; dims all %32 == 0.
// bid < 1280: Wq/Wk/Wv/Wo/Wr (512x512, 256 tiles each)
// bid < 2304: W1 (512x2048 -> 2048x512)
// else      : W2 (2048x512 -> 512x2048)
__global__ __launch_bounds__(256) void transpose_all(
    const float* __restrict__ Wq, const float* __restrict__ Wk,
    const float* __restrict__ Wv, const float* __restrict__ Wo,
    const float* __restrict__ Wr, const float* __restrict__ W1,
    const float* __restrict__ W2, char* __restrict__ wsb)
{
  __shared__ float t[32][33];
  const int bid = blockIdx.x;
  const float* src; u16* dst;
  int ldi, ldo, bx, by;
  if (bid < 1280) {
    const int w = bid >> 8, tl = bid & 255;
    bx = tl & 15; by = tl >> 4; ldi = 512; ldo = 512;
    src = (w == 0) ? Wq : (w == 1) ? Wk : (w == 2) ? Wv : (w == 3) ? Wo : Wr;
    dst = (u16*)(wsb + 2117632 + (int64_t)w * 524288);
  } else if (bid < 2304) {
    const int tl = bid - 1280;
    bx = tl & 63; by = tl >> 6; ldi = 2048; ldo = 512;
    src = W1; dst = (u16*)(wsb + 4739072);
  } else {
    const int tl = bid - 2304;
    bx = tl & 15; by = tl >> 4; ldi = 512; ldo = 2048;
    src = W2; dst = (u16*)(wsb + 6836224);
  }
  const int x = threadIdx.x & 31, y = threadIdx.x >> 5;   // 32 x 8
  const int r0 = by * 32, c0 = bx * 32;
#pragma unroll
  for (int i = 0; i < 32; i += 8)
    t[y + i][x] = src[(int64_t)(r0 + y + i) * ldi + c0 + x];
  __syncthreads();
#pragma unroll
  for (int i = 0; i < 32; i += 8)
    dst[(int64_t)(c0 + y + i) * ldo + r0 + x] = f2bf(t[x][y + i]);
}

// v (b,l,h,dh) bf16 -> vt (b,h,dh,l) bf16;  z = b*8+h
__global__ void transpose_v_kernel(const u16* __restrict__ v, u16* __restrict__ vt) {
  __shared__ u16 t[32][33];
  int z = blockIdx.z;
  const u16* in = v + (int64_t)(z >> 3) * 524288 + (z & 7) * 64;
  u16* out = vt + (int64_t)z * 65536;
  int c0 = blockIdx.x * 32, r0 = blockIdx.y * 32;
  int x = threadIdx.x, y = threadIdx.y;
#pragma unroll
  for (int i = 0; i < 32; i += 8)
    t[y + i][x] = in[(int64_t)(r0 + y + i) * 512 + c0 + x];
  __syncthreads();
#pragma unroll
  for (int i = 0; i < 32; i += 8)
    out[(int64_t)(c0 + y + i) * 1024 + r0 + x] = t[x][y + i];
}

// one wave per 512-elem row; 4 rows / 256-thread block.  grid(1024)
template <int OUT_F32>
__global__ void layernorm_kernel(const float* __restrict__ X,
                                 const float* __restrict__ sc, const float* __restrict__ bi,
                                 void* __restrict__ outv) {
  const int row = blockIdx.x * 4 + (threadIdx.x >> 6);
  const int lane = threadIdx.x & 63;
  const float* x = X + (int64_t)row * 512;
  f32x4 a = ((const f32x4*)x)[lane];
  f32x4 b = ((const f32x4*)x)[lane + 64];
  float s = 0.f, q = 0.f;
#pragma unroll
  for (int e = 0; e < 4; ++e) { s += a[e] + b[e]; q += a[e]*a[e] + b[e]*b[e]; }
#pragma unroll
  for (int o = 32; o; o >>= 1) { s += __shfl_xor(s, o, 64); q += __shfl_xor(q, o, 64); }
  const float mu = s * (1.f / 512.f);
  const float var = q * (1.f / 512.f) - mu * mu;
  const float r = rsqrtf(var + 1e-6f);
  const int c1 = lane * 4, c2 = (lane + 64) * 4;
  f32x4 s1 = ((const f32x4*)sc)[lane],      s2 = ((const f32x4*)sc)[lane + 64];
  f32x4 g1 = ((const f32x4*)bi)[lane],      g2 = ((const f32x4*)bi)[lane + 64];
  if (OUT_F32) {
    float* out = (float*)outv;
    f32x4 o1, o2;
#pragma unroll
    for (int e = 0; e < 4; ++e) {
      o1[e] = (a[e] - mu) * r * s1[e] + g1[e];
      o2[e] = (b[e] - mu) * r * s2[e] + g2[e];
    }
    *(f32x4*)&out[(int64_t)row * 512 + c1] = o1;
    *(f32x4*)&out[(int64_t)row * 512 + c2] = o2;
  } else {
    u16* out = (u16*)outv;
    u16x4 o1, o2;
#pragma unroll
    for (int e = 0; e < 4; ++e) {
      o1[e] = f2bf((a[e] - mu) * r * s1[e] + g1[e]);
      o2[e] = f2bf((b[e] - mu) * r * s2[e] + g2[e]);
    }
    *(u16x4*)&out[(int64_t)row * 512 + c1] = o1;
    *(u16x4*)&out[(int64_t)row * 512 + c2] = o2;
  }
}

// ---------------------------------------------------------------------------
extern "C" void kernel_launch(void* const* d_in, const int* in_sizes, int n_in,
                              void* d_out, int out_size, void* d_ws, size_t ws_size,
                              hipStream_t stream) {
  const float* x    = (const float*)d_in[0];
  const float* Wq   = (const float*)d_in[1];
  const float* bq   = (const float*)d_in[2];
  const float* Wk   = (const float*)d_in[3];
  const float* bk   = (const float*)d_in[4];
  const float* Wv   = (const float*)d_in[5];
  const float* bv   = (const float*)d_in[6];
  const float* cb   = (const float*)d_in[7];
  const float* rb   = (const float*)d_in[8];
  const float* Wr   = (const float*)d_in[9];
  const float* Wo   = (const float*)d_in[10];
  const float* bo   = (const float*)d_in[11];
  const float* ln1s = (const float*)d_in[12];
  const float* ln1b = (const float*)d_in[13];
  const float* W1   = (const float*)d_in[14];
  const float* b1   = (const float*)d_in[15];
  const float* W2   = (const float*)d_in[16];
  const float* b2   = (const float*)d_in[17];
  const float* ln2s = (const float*)d_in[18];
  const float* ln2b = (const float*)d_in[19];
  (void)in_sizes; (void)n_in; (void)out_size; (void)ws_size;

  char* ws = (char*)d_ws;
  float* bqc = (float*)(ws + 0);          // 512 f32
  float* bqr = (float*)(ws + 2048);
  float* bkv = (float*)(ws + 4096);       // 1024 f32 (bk | bv)
  u16* pe  = (u16*)(ws + 20480);          // 2048x512 bf16
  u16* WqT = (u16*)(ws + 2117632);        // 512x512 bf16 each, contiguous
  u16* WkT = (u16*)(ws + 2641920);
  u16* WoT = (u16*)(ws + 3690496);
  u16* WrT = (u16*)(ws + 4214784);
  u16* W1T = (u16*)(ws + 4739072);        // 2048x512
  u16* W2T = (u16*)(ws + 6836224);        // 512x2048
  u16* xb  = (u16*)(ws + 8933376);        // 4096x512 bf16
  u16* qc  = (u16*)(ws + 13127680);       // 4096x512
  u16* qr  = (u16*)(ws + 17321984);
  u16* kb  = (u16*)(ws + 21516288);       // kb | vb contiguous (z-batched)
  u16* vb  = (u16*)(ws + 25710592);
  u16* vt  = (u16*)(ws + 29904896);       // (b,h,dh,l)
  u16* rk  = (u16*)(ws + 34099200);       // 2048x512
  u16* ob  = (u16*)(ws + 36196352);       // 4096x512 (attn out)
  char* scratch = ws + 40390656;
  float* o2   = (float*)scratch;                  // 4096x512 fp32
  u16*   ln1  = (u16*)(scratch + 8388608);        // 4096x512 bf16
  u16*   ffn1 = (u16*)(scratch + 12582912);       // 4096x2048 bf16
  float* f2   = o2;                               // o2 dead after LN1

  const dim3 blk(256), tb(32, 8);

  prep_biases<<<dim3(2), blk, 0, stream>>>(bq, cb, rb, bk, bv, bqc, bqr, bkv);
  pe_kernel<<<dim3(4096), blk, 0, stream>>>(pe);
  convert_f32_bf16<<<dim3(2048), blk, 0, stream>>>(x, xb);
  transpose_all<<<dim3(3328), blk, 0, stream>>>(Wq, Wk, Wv, Wo, Wr, W1, W2, ws);

  // projections: q (dual out), k+v z-batched, rk
  gemm_bt<EPI_BF16_DUAL, 2><<<dim3(8, 32, 1), blk, 0, stream>>>(
      xb, 0, 512, WqT, 0, 512, (char*)qc, 0, 512, (char*)qr,
      bqc, 0, bqr, 4096, 512, 512);
  gemm_bt<EPI_BF16, 2><<<dim3(8, 32, 2), blk, 0, stream>>>(
      xb, 0, 512, WkT, 262144, 512, (char*)kb, 4194304, 512, nullptr,
      bkv, 512, nullptr, 4096, 512, 512);
  gemm_bt<EPI_BF16, 2><<<dim3(8, 16, 1), blk, 0, stream>>>(
      pe, 0, 512, WrT, 0, 512, (char*)rk, 0, 512, nullptr,
      nullptr, 0, nullptr, 2048, 512, 512);
  transpose_v_kernel<<<dim3(2, 32, 32), tb, 0, stream>>>(vb, vt);

  // fused attention
  fused_attn_kernel<<<dim3(16, 8, 4), blk, 0, stream>>>(qc, qr, kb, vt, rk, ob);

  // o@Wo + bo, doubled -> fp32
  gemm_bt<EPI_F32_X2, 2><<<dim3(8, 32, 1), blk, 0, stream>>>(
      ob, 0, 512, WoT, 0, 512, (char*)o2, 0, 512, nullptr,
      bo, 0, nullptr, 4096, 512, 512);
  layernorm_kernel<0><<<dim3(1024), blk, 0, stream>>>(o2, ln1s, ln1b, ln1);
  // FFN
  gemm_bt<EPI_BF16_RELU, 4><<<dim3(16, 32, 1), blk, 0, stream>>>(
      ln1, 0, 512, W1T, 0, 512, (char*)ffn1, 0, 2048, nullptr,
      b1, 0, nullptr, 4096, 2048, 512);
  gemm_bt<EPI_F32_X2, 2><<<dim3(8, 32, 1), blk, 0, stream>>>(
      ffn1, 0, 2048, W2T, 0, 2048, (char*)f2, 0, 512, nullptr,
      b2, 0, nullptr, 4096, 512, 2048);
  layernorm_kernel<1><<<dim3(1024), blk, 0, stream>>>(f2, ln2s, ln2b, d_out);
}

// Round 7
// 192.670 us; speedup vs baseline: 3.1582x; 1.0647x over previous
//
#include <hip/hip_runtime.h>
#include <stdint.h>

// ---------------------------------------------------------------------------
// TransformerXL encoder layer.  Inputs fp32, OUTPUT fp32.  b=4 l=1024 d=512
// h=8 dh=64.
// Round 7: attn occupancy attack.  (1) rLds scatter-merge -> register
// shuffles (LDS 62.5->40KB), (2) T14 rotated loop (prefetch under compute),
// (3) XCD-aware block decode (XCD = head), (4) fused QKV projection GEMM,
// (5) fast-math trig in pe.
// rel shift closed form: shifted[t,j] = R[t, 1024 + j - t],  R = (q+rb)@rk^T.
// ---------------------------------------------------------------------------

typedef unsigned short u16;
typedef __attribute__((ext_vector_type(8))) __bf16 bf16x8;
typedef __attribute__((ext_vector_type(8))) unsigned short u16x8;
typedef __attribute__((ext_vector_type(4))) float f32x4;
typedef __attribute__((ext_vector_type(4))) unsigned short u16x4;

#define BK 64

static __device__ __forceinline__ u16 f2bf(float f) {
  union { float f; unsigned int i; } v; v.f = f;
  unsigned int r = v.i + 0x7FFFu + ((v.i >> 16) & 1u);
  return (u16)(r >> 16);
}

// global->LDS direct copy, 16B per lane (lds dest must be linear in lane id).
static __device__ __forceinline__ void gld16(const void* g, void* l) {
  __builtin_amdgcn_global_load_lds(
      (__attribute__((address_space(1))) void*)(uintptr_t)g,
      (__attribute__((address_space(3))) void*)(uintptr_t)l,
      16, 0, 0);
}

// swizzled u16 index into a [rows][64]-u16 LDS tile (16B chunk ^= row&7).
static __device__ __forceinline__ int swzIdx(int r, int ch) {
  return (r << 6) + (((ch ^ (r & 7)) & 7) << 3);
}

// ---------------------------------------------------------------------------
// Fused attention.  512 blocks 1-D, decoded so XCD (= bid&7) == head:
// bid = h + 8*qt + 128*b.  Per block: 64 q-rows, 16 kv-tiles of 64.
// T14: prefetch tile it+1 regs under compute of tile it.
// Band merge via shuffles: R[rw, c] owner lane = (c&15)|(g<<4), reg j,
// fragment c>>4 in {n, n+1}; src/select independent of n.
// ---------------------------------------------------------------------------
__global__ __launch_bounds__(256) void fused_attn_kernel(
    const u16* __restrict__ qc, const u16* __restrict__ qr,
    const u16* __restrict__ kb, const u16* __restrict__ vt,
    const u16* __restrict__ rk, u16* __restrict__ ob)
{
  __shared__ __align__(16) u16 kbLds[64 * 64];    // k tile  [j][d]
  __shared__ __align__(16) u16 vtLds[64 * 64];    // vt tile [c][j]
  __shared__ __align__(16) u16 rkLds[128 * 64];   // rk band [lr][d]
  __shared__ __align__(16) u16 pLds[4][16 * 64];  // per-wave P [ttw][j]

  const int tid  = threadIdx.x;
  const int lane = tid & 63;
  const int w    = tid >> 6;
  const int g    = lane >> 4;
  const int li   = lane & 15;

  const int bid = blockIdx.x;          // XCD = bid&7 = h (all of head h on one XCD)
  const int h   = bid & 7;
  const int s   = bid >> 3;
  const int t0  = (s & 15) * 64;
  const int b   = s >> 4;

  const int64_t qoff = (int64_t)b * 524288 + (int64_t)(t0 + w * 16 + li) * 512
                     + h * 64 + g * 8;
  bf16x8 qcf[2], qrf[2];
  qcf[0] = *(const bf16x8*)(qc + qoff);
  qcf[1] = *(const bf16x8*)(qc + qoff + 32);
  qrf[0] = *(const bf16x8*)(qr + qoff);
  qrf[1] = *(const bf16x8*)(qr + qoff + 32);

  const u16* kbB = kb + (int64_t)b * 524288 + h * 64;
  const u16* vtB = vt + (int64_t)(b * 8 + h) * 65536;
  const u16* rkB = rk + h * 64;

  float m_[4] = {-1e30f, -1e30f, -1e30f, -1e30f};
  float l_[4] = {0.f, 0.f, 0.f, 0.f};
  f32x4 o_[4];
#pragma unroll
  for (int n = 0; n < 4; ++n) o_[n] = (f32x4){0.f, 0.f, 0.f, 0.f};

  // per-lane band-merge constants (independent of n; see derivation)
  const int base = li - 4 * g + 15;            // in [3,30]
  int  srcj[4];
  bool cndj[4];
#pragma unroll
  for (int j = 0; j < 4; ++j) {
    srcj[j] = ((base - j) & 15) | (lane & 48);
    cndj[j] = (base - j) < 16;
  }

  // staging regs (T14: loaded one tile ahead)
  u16x8 sk[2], svv[2], srr[4];
  auto ISSUE = [&](int itx) {
    const int j0 = itx * 64;
    const int ub = 1024 + j0 - t0 - 63;        // >= 1
#pragma unroll
    for (int p = 0; p < 2; ++p) {
      const int flat = p * 256 + tid, r = flat >> 3, ch = flat & 7;
      sk[p]  = *(const u16x8*)(kbB + (int64_t)(j0 + r) * 512 + ch * 8);
      svv[p] = *(const u16x8*)(vtB + (int64_t)r * 1024 + j0 + ch * 8);
    }
#pragma unroll
    for (int p = 0; p < 4; ++p) {
      const int flat = p * 256 + tid, r = flat >> 3, ch = flat & 7;
      int u = ub + r; u = u < 2047 ? u : 2047;
      srr[p] = *(const u16x8*)(rkB + (int64_t)u * 512 + ch * 8);
    }
  };

  ISSUE(0);
  for (int it = 0; it < 16; ++it) {
    __syncthreads();   // barrier_A: prev compute's LDS reads done; vmcnt drained
#pragma unroll
    for (int p = 0; p < 2; ++p) {
      const int flat = p * 256 + tid, r = flat >> 3, ch = flat & 7;
      *(u16x8*)&kbLds[swzIdx(r, ch)] = sk[p];
      *(u16x8*)&vtLds[swzIdx(r, ch)] = svv[p];
    }
#pragma unroll
    for (int p = 0; p < 4; ++p) {
      const int flat = p * 256 + tid, r = flat >> 3, ch = flat & 7;
      *(u16x8*)&rkLds[swzIdx(r, ch)] = srr[p];
    }
    __syncthreads();   // barrier_B: tile visible
    if (it < 15) ISSUE(it + 1);   // prefetch flies under the compute below

    // ---- content logits C[t, jj] ----
    f32x4 c_[4];
#pragma unroll
    for (int n = 0; n < 4; ++n) c_[n] = (f32x4){0.f, 0.f, 0.f, 0.f};
#pragma unroll
    for (int kc = 0; kc < 2; ++kc) {
      const int chn = kc * 4 + g;
#pragma unroll
      for (int n = 0; n < 4; ++n) {
        bf16x8 bb = *(const bf16x8*)&kbLds[swzIdx(n * 16 + li, chn)];
        c_[n] = __builtin_amdgcn_mfma_f32_16x16x32_bf16(qcf[kc], bb, c_[n], 0, 0, 0);
      }
    }
    // ---- rel band R[t, c], c in [0,80) per wave ----
    f32x4 r_[5];
#pragma unroll
    for (int f = 0; f < 5; ++f) r_[f] = (f32x4){0.f, 0.f, 0.f, 0.f};
#pragma unroll
    for (int kc = 0; kc < 2; ++kc) {
      const int chn = kc * 4 + g;
#pragma unroll
      for (int f = 0; f < 5; ++f) {
        const int lr = f * 16 + li + 48 - 16 * w;
        bf16x8 bb = *(const bf16x8*)&rkLds[swzIdx(lr, chn)];
        r_[f] = __builtin_amdgcn_mfma_f32_16x16x32_bf16(qrf[kc], bb, r_[f], 0, 0, 0);
      }
    }
    // ---- band merge via shuffles: S = C + R[rw, col-rw+15] ----
    float sv2[4][4];
#pragma unroll
    for (int n = 0; n < 4; ++n)
#pragma unroll
      for (int j = 0; j < 4; ++j) {
        const float v0 = __shfl(r_[n][j],     srcj[j], 64);
        const float v1 = __shfl(r_[n + 1 < 5 ? n + 1 : 4][j], srcj[j], 64);
        sv2[n][j] = c_[n][j] + (cndj[j] ? v0 : v1);
      }

    // ---- online softmax (row = g*4+j over 16 lanes) ----
    float al[4], rs[4];
#pragma unroll
    for (int j = 0; j < 4; ++j) {
      float t = fmaxf(fmaxf(sv2[0][j], sv2[1][j]), fmaxf(sv2[2][j], sv2[3][j]));
#pragma unroll
      for (int off = 1; off < 16; off <<= 1) t = fmaxf(t, __shfl_xor(t, off, 64));
      const float nm = fmaxf(m_[j], t);
      al[j] = __expf(m_[j] - nm);
      m_[j] = nm;
      rs[j] = 0.f;
    }
    u16* pw = pLds[w];
#pragma unroll
    for (int n = 0; n < 4; ++n)
#pragma unroll
      for (int j = 0; j < 4; ++j) {
        const float p = __expf(sv2[n][j] - m_[j]);
        rs[j] += p;
        const int rw = g * 4 + j, col = n * 16 + li;
        pw[(rw << 6) + ((((col >> 3) ^ (rw & 7)) & 7) << 3) + (col & 7)] = f2bf(p);
      }
#pragma unroll
    for (int j = 0; j < 4; ++j) {
      float t = rs[j];
#pragma unroll
      for (int off = 1; off < 16; off <<= 1) t += __shfl_xor(t, off, 64);
      l_[j] = l_[j] * al[j] + t;
    }
#pragma unroll
    for (int n = 0; n < 4; ++n)
#pragma unroll
      for (int j = 0; j < 4; ++j) o_[n][j] *= al[j];

    // ---- PV ----
#pragma unroll
    for (int kc = 0; kc < 2; ++kc) {
      const int chn = kc * 4 + g;
      bf16x8 pa = *(const bf16x8*)&pw[swzIdx(li, chn)];
#pragma unroll
      for (int n = 0; n < 4; ++n) {
        bf16x8 vb = *(const bf16x8*)&vtLds[swzIdx(n * 16 + li, chn)];
        o_[n] = __builtin_amdgcn_mfma_f32_16x16x32_bf16(pa, vb, o_[n], 0, 0, 0);
      }
    }
  }

  float inv[4];
#pragma unroll
  for (int j = 0; j < 4; ++j) inv[j] = 1.f / l_[j];
  u16* obB = ob + (int64_t)b * 524288 + (int64_t)(t0 + w * 16) * 512 + h * 64;
#pragma unroll
  for (int n = 0; n < 4; ++n)
#pragma unroll
    for (int j = 0; j < 4; ++j)
      obB[(int64_t)(g * 4 + j) * 512 + n * 16 + li] = f2bf(o_[n][j] * inv[j]);
}

enum { EPI_BF16 = 0, EPI_BF16_RELU = 1, EPI_F32_X2 = 5, EPI_QKV = 6 };

// C[m,n] = sum_k A[m,k] * Bt[n,k].  Tile 128 x (NW*32): 4 waves (2M x 2N),
// per-wave 64 x (NW*16), acc[4][NW].  global_load_lds width-16 staging.
// EPI_QKV: N=1536 over WqT|WkT|WvT; outputs qc/qr/kb/vb at Cb + slot*2097152
// (u16), biases bqc|bqr|bk|bv contiguous at bias1.
template <int EPI, int NW>
__global__ __launch_bounds__(256) void gemm_bt(
    const u16* __restrict__ A, int64_t zA, int lda,
    const u16* __restrict__ Bt, int64_t zB, int ldb,
    char* __restrict__ Cb, int64_t zCbytes, int ldc,
    const float* __restrict__ bias1, int zbias,
    int M, int N, int K)
{
  __shared__ __align__(16) u16 As[128 * BK];
  __shared__ __align__(16) u16 Bs[NW * 32 * BK];

  const int z = blockIdx.z;
  A  += (int64_t)z * zA;
  Bt += (int64_t)z * zB;
  Cb += (int64_t)z * zCbytes;

  const int m0 = blockIdx.y * 128;
  const int n0 = blockIdx.x * (NW * 32);

  const int tid  = threadIdx.x;
  const int lane = tid & 63;
  const int wid  = tid >> 6;
  const int wm = (wid >> 1) * 64;
  const int wn = (wid & 1) * (NW * 16);
  const int fr = lane & 15;
  const int fk = (lane >> 4) * 8;

  f32x4 acc[4][NW];
#pragma unroll
  for (int m = 0; m < 4; ++m)
#pragma unroll
    for (int n = 0; n < NW; ++n) acc[m][n] = (f32x4){0.f, 0.f, 0.f, 0.f};

  for (int kt = 0; kt < K; kt += BK) {
    __syncthreads();
#pragma unroll
    for (int it = 0; it < 4; ++it) {
      const int off = (it * 256 + tid) * 8;
      const int r = off >> 6, c = off & (BK - 1);
      int gr = m0 + r; if (gr > M - 1) gr = M - 1;
      gld16(A + (int64_t)gr * lda + kt + c, &As[off]);
    }
#pragma unroll
    for (int it = 0; it < NW; ++it) {
      const int off = (it * 256 + tid) * 8;
      const int r = off >> 6, c = off & (BK - 1);
      int gr = n0 + r; if (gr > N - 1) gr = N - 1;
      gld16(Bt + (int64_t)gr * ldb + kt + c, &Bs[off]);
    }
    __syncthreads();

#pragma unroll
    for (int kk = 0; kk < BK; kk += 32) {
      bf16x8 af[4], bfv[NW];
#pragma unroll
      for (int m = 0; m < 4; ++m)
        af[m] = *(const bf16x8*)&As[(wm + m * 16 + fr) * BK + kk + fk];
#pragma unroll
      for (int n = 0; n < NW; ++n)
        bfv[n] = *(const bf16x8*)&Bs[(wn + n * 16 + fr) * BK + kk + fk];
#pragma unroll
      for (int m = 0; m < 4; ++m)
#pragma unroll
        for (int n = 0; n < NW; ++n)
          acc[m][n] = __builtin_amdgcn_mfma_f32_16x16x32_bf16(af[m], bfv[n], acc[m][n], 0, 0, 0);
    }
  }

  const int r0 = m0 + wm + (lane >> 4) * 4;
  const int c0 = n0 + wn + fr;
#pragma unroll
  for (int m = 0; m < 4; ++m) {
#pragma unroll
    for (int n = 0; n < NW; ++n) {
      const int col = c0 + n * 16;
      if (col >= N) continue;
      float b1v = 0.f;
      if (EPI == EPI_BF16 || EPI == EPI_BF16_RELU || EPI == EPI_F32_X2) {
        if (bias1) b1v = bias1[z * zbias + col];
      }
#pragma unroll
      for (int j = 0; j < 4; ++j) {
        const int row = r0 + m * 16 + j;
        if (row >= M) continue;
        const float v = acc[m][n][j];
        if (EPI == EPI_BF16) {
          ((u16*)Cb)[(int64_t)row * ldc + col] = f2bf(v + b1v);
        } else if (EPI == EPI_BF16_RELU) {
          float t = v + b1v; t = t > 0.f ? t : 0.f;
          ((u16*)Cb)[(int64_t)row * ldc + col] = f2bf(t);
        } else if (EPI == EPI_F32_X2) {
          ((float*)Cb)[(int64_t)row * ldc + col] = 2.f * (v + b1v);
        } else if (EPI == EPI_QKV) {
          const int which = col >> 9, cc = col & 511;
          const int slot = (which == 0) ? 0 : which + 1;   // 0:qc 2:kb 3:vb
          u16* dst = (u16*)Cb + (int64_t)slot * 2097152 + (int64_t)row * 512 + cc;
          *dst = f2bf(v + bias1[slot * 512 + cc]);
          if (which == 0)                                   // slot 1: qr
            dst[2097152] = f2bf(v + bias1[512 + cc]);
        }
      }
    }
  }
}

__global__ void convert_f32_bf16(const float* __restrict__ in, u16* __restrict__ out) {
  int idx = blockIdx.x * 256 + threadIdx.x;
  f32x4 v = ((const f32x4*)in)[idx];
  u16x4 o;
  o[0] = f2bf(v[0]); o[1] = f2bf(v[1]); o[2] = f2bf(v[2]); o[3] = f2bf(v[3]);
  ((u16x4*)out)[idx] = o;
}

// combined q biases + packed k/v biases (bqc|bqr|bk|bv contiguous)
__global__ void prep_biases(const float* bq, const float* cb, const float* rb,
                            const float* bk, const float* bv,
                            float* bqc, float* bqr, float* bkv)
{
  int i = blockIdx.x * 256 + threadIdx.x;
  if (i < 512) {
    bqc[i] = bq[i] + cb[i];
    bqr[i] = bq[i] + rb[i];
    bkv[i] = bk[i];
    bkv[512 + i] = bv[i];
  }
}

// pe[i][j]: pos = i-1024; jf = j&255; inv = 10000^(-2*jf/512); sin | cos
__global__ void pe_kernel(u16* pe) {
  int idx = blockIdx.x * 256 + threadIdx.x;
  int i = idx >> 9, j = idx & 511, jf = j & 255;
  float inv = __expf(-(float)jf * (2.0f / 512.0f) * 9.210340371976184f); // ln 1e4
  float arg = (float)(i - 1024) * inv;
  pe[idx] = f2bf((j < 256) ? __sinf(arg) : __cosf(arg));
}

// ALL weight transposes in one dispatch.  32x32 tiles; dims all %32 == 0.
__global__ __launch_bounds__(256) void transpose_all(
    const float* __restrict__ Wq, const float* __restrict__ Wk,
    const float* __restrict__ Wv, const float* __restrict__ Wo,
    const float* __restrict__ Wr, const float* __restrict__ W1,
    const float* __restrict__ W2, char* __restrict__ wsb)
{
  __shared__ float t[32][33];
  const int bid = blockIdx.x;
  const float* src; u16* dst;
  int ldi, ldo, bx, by;
  if (bid < 1280) {
    const int w = bid >> 8, tl = bid & 255;
    bx = tl & 15; by = tl >> 4; ldi = 512; ldo = 512;
    src = (w == 0) ? Wq : (w == 1) ? Wk : (w == 2) ? Wv : (w == 3) ? Wo : Wr;
    dst = (u16*)(wsb + 2117632 + (int64_t)w * 524288);
  } else if (bid < 2304) {
    const int tl = bid - 1280;
    bx = tl & 63; by = tl >> 6; ldi = 2048; ldo = 512;
    src = W1; dst = (u16*)(wsb + 4739072);
  } else {
    const int tl = bid - 2304;
    bx = tl & 15; by = tl >> 4; ldi = 512; ldo = 2048;
    src = W2; dst = (u16*)(wsb + 6836224);
  }
  const int x = threadIdx.x & 31, y = threadIdx.x >> 5;   // 32 x 8
  const int r0 = by * 32, c0 = bx * 32;
#pragma unroll
  for (int i = 0; i < 32; i += 8)
    t[y + i][x] = src[(int64_t)(r0 + y + i) * ldi + c0 + x];
  __syncthreads();
#pragma unroll
  for (int i = 0; i < 32; i += 8)
    dst[(int64_t)(c0 + y + i) * ldo + r0 + x] = f2bf(t[x][y + i]);
}

// v (b,l,h,dh) bf16 -> vt (b,h,dh,l) bf16;  z = b*8+h
__global__ void transpose_v_kernel(const u16* __restrict__ v, u16* __restrict__ vt) {
  __shared__ u16 t[32][33];
  int z = blockIdx.z;
  const u16* in = v + (int64_t)(z >> 3) * 524288 + (z & 7) * 64;
  u16* out = vt + (int64_t)z * 65536;
  int c0 = blockIdx.x * 32, r0 = blockIdx.y * 32;
  int x = threadIdx.x, y = threadIdx.y;
#pragma unroll
  for (int i = 0; i < 32; i += 8)
    t[y + i][x] = in[(int64_t)(r0 + y + i) * 512 + c0 + x];
  __syncthreads();
#pragma unroll
  for (int i = 0; i < 32; i += 8)
    out[(int64_t)(c0 + y + i) * 1024 + r0 + x] = t[x][y + i];
}

// one wave per 512-elem row; 4 rows / 256-thread block.  grid(1024)
template <int OUT_F32>
__global__ void layernorm_kernel(const float* __restrict__ X,
                                 const float* __restrict__ sc, const float* __restrict__ bi,
                                 void* __restrict__ outv) {
  const int row = blockIdx.x * 4 + (threadIdx.x >> 6);
  const int lane = threadIdx.x & 63;
  const float* x = X + (int64_t)row * 512;
  f32x4 a = ((const f32x4*)x)[lane];
  f32x4 b = ((const f32x4*)x)[lane + 64];
  float s = 0.f, q = 0.f;
#pragma unroll
  for (int e = 0; e < 4; ++e) { s += a[e] + b[e]; q += a[e]*a[e] + b[e]*b[e]; }
#pragma unroll
  for (int o = 32; o; o >>= 1) { s += __shfl_xor(s, o, 64); q += __shfl_xor(q, o, 64); }
  const float mu = s * (1.f / 512.f);
  const float var = q * (1.f / 512.f) - mu * mu;
  const float r = rsqrtf(var + 1e-6f);
  const int c1 = lane * 4, c2 = (lane + 64) * 4;
  f32x4 s1 = ((const f32x4*)sc)[lane],      s2 = ((const f32x4*)sc)[lane + 64];
  f32x4 g1 = ((const f32x4*)bi)[lane],      g2 = ((const f32x4*)bi)[lane + 64];
  if (OUT_F32) {
    float* out = (float*)outv;
    f32x4 o1, o2;
#pragma unroll
    for (int e = 0; e < 4; ++e) {
      o1[e] = (a[e] - mu) * r * s1[e] + g1[e];
      o2[e] = (b[e] - mu) * r * s2[e] + g2[e];
    }
    *(f32x4*)&out[(int64_t)row * 512 + c1] = o1;
    *(f32x4*)&out[(int64_t)row * 512 + c2] = o2;
  } else {
    u16* out = (u16*)outv;
    u16x4 o1, o2;
#pragma unroll
    for (int e = 0; e < 4; ++e) {
      o1[e] = f2bf((a[e] - mu) * r * s1[e] + g1[e]);
      o2[e] = f2bf((b[e] - mu) * r * s2[e] + g2[e]);
    }
    *(u16x4*)&out[(int64_t)row * 512 + c1] = o1;
    *(u16x4*)&out[(int64_t)row * 512 + c2] = o2;
  }
}

// ---------------------------------------------------------------------------
extern "C" void kernel_launch(void* const* d_in, const int* in_sizes, int n_in,
                              void* d_out, int out_size, void* d_ws, size_t ws_size,
                              hipStream_t stream) {
  const float* x    = (const float*)d_in[0];
  const float* Wq   = (const float*)d_in[1];
  const float* bq   = (const float*)d_in[2];
  const float* Wk   = (const float*)d_in[3];
  const float* bk   = (const float*)d_in[4];
  const float* Wv   = (const float*)d_in[5];
  const float* bv   = (const float*)d_in[6];
  const float* cb   = (const float*)d_in[7];
  const float* rb   = (const float*)d_in[8];
  const float* Wr   = (const float*)d_in[9];
  const float* Wo   = (const float*)d_in[10];
  const float* bo   = (const float*)d_in[11];
  const float* ln1s = (const float*)d_in[12];
  const float* ln1b = (const float*)d_in[13];
  const float* W1   = (const float*)d_in[14];
  const float* b1   = (const float*)d_in[15];
  const float* W2   = (const float*)d_in[16];
  const float* b2   = (const float*)d_in[17];
  const float* ln2s = (const float*)d_in[18];
  const float* ln2b = (const float*)d_in[19];
  (void)in_sizes; (void)n_in; (void)out_size; (void)ws_size;

  char* ws = (char*)d_ws;
  float* bqc = (float*)(ws + 0);          // bqc|bqr|bkv contiguous (2048 f32)
  float* bqr = (float*)(ws + 2048);
  float* bkv = (float*)(ws + 4096);
  u16* pe  = (u16*)(ws + 20480);          // 2048x512 bf16
  u16* WqT = (u16*)(ws + 2117632);        // Wq|Wk|Wv T contiguous (1536x512)
  u16* WoT = (u16*)(ws + 3690496);
  u16* WrT = (u16*)(ws + 4214784);
  u16* W1T = (u16*)(ws + 4739072);        // 2048x512
  u16* W2T = (u16*)(ws + 6836224);        // 512x2048
  u16* xb  = (u16*)(ws + 8933376);        // 4096x512 bf16
  u16* qc  = (u16*)(ws + 13127680);       // qc|qr|kb|vb each +2097152 u16
  u16* kb  = (u16*)(ws + 21516288);
  u16* vb  = (u16*)(ws + 25710592);
  u16* vt  = (u16*)(ws + 29904896);       // (b,h,dh,l)
  u16* rk  = (u16*)(ws + 34099200);       // 2048x512
  u16* ob  = (u16*)(ws + 36196352);       // 4096x512 (attn out)
  char* scratch = ws + 40390656;
  float* o2   = (float*)scratch;                  // 4096x512 fp32
  u16*   ln1  = (u16*)(scratch + 8388608);        // 4096x512 bf16
  u16*   ffn1 = (u16*)(scratch + 12582912);       // 4096x2048 bf16
  float* f2   = o2;                               // o2 dead after LN1

  const dim3 blk(256), tb(32, 8);

  prep_biases<<<dim3(2), blk, 0, stream>>>(bq, cb, rb, bk, bv, bqc, bqr, bkv);
  pe_kernel<<<dim3(4096), blk, 0, stream>>>(pe);
  convert_f32_bf16<<<dim3(2048), blk, 0, stream>>>(x, xb);
  transpose_all<<<dim3(3328), blk, 0, stream>>>(Wq, Wk, Wv, Wo, Wr, W1, W2, ws);

  // fused q/qr/k/v projection (N = 1536 over WqT|WkT|WvT)
  gemm_bt<EPI_QKV, 2><<<dim3(24, 32, 1), blk, 0, stream>>>(
      xb, 0, 512, WqT, 0, 512, (char*)qc, 0, 512, bqc, 0, 4096, 1536, 512);
  gemm_bt<EPI_BF16, 2><<<dim3(8, 16, 1), blk, 0, stream>>>(
      pe, 0, 512, WrT, 0, 512, (char*)rk, 0, 512, nullptr, 0, 2048, 512, 512);
  transpose_v_kernel<<<dim3(2, 32, 32), tb, 0, stream>>>(vb, vt);

  // fused attention (XCD-aware 1-D grid)
  fused_attn_kernel<<<dim3(512), blk, 0, stream>>>(qc, qc + 2097152, kb, vt, rk, ob);

  // o@Wo + bo, doubled -> fp32
  gemm_bt<EPI_F32_X2, 2><<<dim3(8, 32, 1), blk, 0, stream>>>(
      ob, 0, 512, WoT, 0, 512, (char*)o2, 0, 512, bo, 0, 4096, 512, 512);
  layernorm_kernel<0><<<dim3(1024), blk, 0, stream>>>(o2, ln1s, ln1b, ln1);
  // FFN
  gemm_bt<EPI_BF16_RELU, 4><<<dim3(16, 32, 1), blk, 0, stream>>>(
      ln1, 0, 512, W1T, 0, 512, (char*)ffn1, 0, 2048, b1, 0, 4096, 2048, 512);
  gemm_bt<EPI_F32_X2, 2><<<dim3(8, 32, 1), blk, 0, stream>>>(
      ffn1, 0, 2048, W2T, 0, 2048, (char*)f2, 0, 512, b2, 0, 4096, 512, 2048);
  layernorm_kernel<1><<<dim3(1024), blk, 0, stream>>>(f2, ln2s, ln2b, d_out);
}

// Round 8
// 163.710 us; speedup vs baseline: 3.7169x; 1.1769x over previous
//
#include <hip/hip_runtime.h>
#include <stdint.h>

// ---------------------------------------------------------------------------
// TransformerXL encoder layer.  Inputs fp32, OUTPUT fp32.  b=4 l=1024 d=512
// h=8 dh=64.
// Round 8: attn LDS-pipe cuts (ones-col PV for l, bpermute 32->20, exact
// defer-rescale) + tail restructure (prep_all uber-kernel, K-split Wo/FFN2
// with fused sum-LN).
// rel shift closed form: shifted[t,j] = R[t, 1024 + j - t],  R = (q+rb)@rk^T.
// ---------------------------------------------------------------------------

typedef unsigned short u16;
typedef __attribute__((ext_vector_type(8))) __bf16 bf16x8;
typedef __attribute__((ext_vector_type(8))) unsigned short u16x8;
typedef __attribute__((ext_vector_type(4))) float f32x4;
typedef __attribute__((ext_vector_type(4))) unsigned short u16x4;

#define BK 64

static __device__ __forceinline__ u16 f2bf(float f) {
  union { float f; unsigned int i; } v; v.f = f;
  unsigned int r = v.i + 0x7FFFu + ((v.i >> 16) & 1u);
  return (u16)(r >> 16);
}

// global->LDS direct copy, 16B per lane (lds dest must be linear in lane id).
static __device__ __forceinline__ void gld16(const void* g, void* l) {
  __builtin_amdgcn_global_load_lds(
      (__attribute__((address_space(1))) void*)(uintptr_t)g,
      (__attribute__((address_space(3))) void*)(uintptr_t)l,
      16, 0, 0);
}

// swizzled u16 index into a [rows][64]-u16 LDS tile (16B chunk ^= row&7).
static __device__ __forceinline__ int swzIdx(int r, int ch) {
  return (r << 6) + (((ch ^ (r & 7)) & 7) << 3);
}

// ---------------------------------------------------------------------------
// Fused attention.  512 blocks 1-D, decoded so XCD (= bid&7) == head.
// Per block: 64 q-rows, 16 kv-tiles of 64.  T14 prefetch; band merge via 20
// bpermutes; l via ones-column PV MFMA (no sum-reduce); exact defer-rescale.
// ---------------------------------------------------------------------------
__global__ __launch_bounds__(256) void fused_attn_kernel(
    const u16* __restrict__ qc, const u16* __restrict__ qr,
    const u16* __restrict__ kb, const u16* __restrict__ vt,
    const u16* __restrict__ rk, u16* __restrict__ ob)
{
  __shared__ __align__(16) u16 kbLds[64 * 64];    // k tile  [j][d]
  __shared__ __align__(16) u16 vtLds[64 * 64];    // vt tile [c][j]
  __shared__ __align__(16) u16 rkLds[128 * 64];   // rk band [lr][d]
  __shared__ __align__(16) u16 pLds[4][16 * 64];  // per-wave P [ttw][j]

  const int tid  = threadIdx.x;
  const int lane = tid & 63;
  const int w    = tid >> 6;
  const int g    = lane >> 4;
  const int li   = lane & 15;

  const int bid = blockIdx.x;          // XCD = bid&7 = h
  const int h   = bid & 7;
  const int s   = bid >> 3;
  const int t0  = (s & 15) * 64;
  const int b   = s >> 4;

  const int64_t qoff = (int64_t)b * 524288 + (int64_t)(t0 + w * 16 + li) * 512
                     + h * 64 + g * 8;
  bf16x8 qcf[2], qrf[2];
  qcf[0] = *(const bf16x8*)(qc + qoff);
  qcf[1] = *(const bf16x8*)(qc + qoff + 32);
  qrf[0] = *(const bf16x8*)(qr + qoff);
  qrf[1] = *(const bf16x8*)(qr + qoff + 32);

  const u16* kbB = kb + (int64_t)b * 524288 + h * 64;
  const u16* vtB = vt + (int64_t)(b * 8 + h) * 65536;
  const u16* rkB = rk + h * 64;

  // all-ones B-frag (bf16 1.0 = 0x3F80) for the l-accumulating MFMA
  bf16x8 ones;
#pragma unroll
  for (int e = 0; e < 8; ++e) ((u16*)&ones)[e] = 0x3F80;

  float m_[4] = {-1e30f, -1e30f, -1e30f, -1e30f};
  f32x4 o_[4];
  f32x4 o4 = (f32x4){0.f, 0.f, 0.f, 0.f};        // row-sum accumulator (= l)
#pragma unroll
  for (int n = 0; n < 4; ++n) o_[n] = (f32x4){0.f, 0.f, 0.f, 0.f};

  // per-lane band-merge constants
  const int base = li - 4 * g + 15;            // in [3,30]
  int  srcj[4];
  bool cndj[4];
#pragma unroll
  for (int j = 0; j < 4; ++j) {
    srcj[j] = ((base - j) & 15) | (lane & 48);
    cndj[j] = (base - j) < 16;
  }

  u16x8 sk[2], svv[2], srr[4];
  auto ISSUE = [&](int itx) {
    const int j0 = itx * 64;
    const int ub = 1024 + j0 - t0 - 63;        // >= 1
#pragma unroll
    for (int p = 0; p < 2; ++p) {
      const int flat = p * 256 + tid, r = flat >> 3, ch = flat & 7;
      sk[p]  = *(const u16x8*)(kbB + (int64_t)(j0 + r) * 512 + ch * 8);
      svv[p] = *(const u16x8*)(vtB + (int64_t)r * 1024 + j0 + ch * 8);
    }
#pragma unroll
    for (int p = 0; p < 4; ++p) {
      const int flat = p * 256 + tid, r = flat >> 3, ch = flat & 7;
      int u = ub + r; u = u < 2047 ? u : 2047;
      srr[p] = *(const u16x8*)(rkB + (int64_t)u * 512 + ch * 8);
    }
  };

  ISSUE(0);
  for (int it = 0; it < 16; ++it) {
    __syncthreads();   // prev compute's LDS reads done
#pragma unroll
    for (int p = 0; p < 2; ++p) {
      const int flat = p * 256 + tid, r = flat >> 3, ch = flat & 7;
      *(u16x8*)&kbLds[swzIdx(r, ch)] = sk[p];
      *(u16x8*)&vtLds[swzIdx(r, ch)] = svv[p];
    }
#pragma unroll
    for (int p = 0; p < 4; ++p) {
      const int flat = p * 256 + tid, r = flat >> 3, ch = flat & 7;
      *(u16x8*)&rkLds[swzIdx(r, ch)] = srr[p];
    }
    __syncthreads();   // tile visible
    if (it < 15) ISSUE(it + 1);   // prefetch flies under compute

    // ---- content logits ----
    f32x4 c_[4];
#pragma unroll
    for (int n = 0; n < 4; ++n) c_[n] = (f32x4){0.f, 0.f, 0.f, 0.f};
#pragma unroll
    for (int kc = 0; kc < 2; ++kc) {
      const int chn = kc * 4 + g;
#pragma unroll
      for (int n = 0; n < 4; ++n) {
        bf16x8 bb = *(const bf16x8*)&kbLds[swzIdx(n * 16 + li, chn)];
        c_[n] = __builtin_amdgcn_mfma_f32_16x16x32_bf16(qcf[kc], bb, c_[n], 0, 0, 0);
      }
    }
    // ---- rel band ----
    f32x4 r_[5];
#pragma unroll
    for (int f = 0; f < 5; ++f) r_[f] = (f32x4){0.f, 0.f, 0.f, 0.f};
#pragma unroll
    for (int kc = 0; kc < 2; ++kc) {
      const int chn = kc * 4 + g;
#pragma unroll
      for (int f = 0; f < 5; ++f) {
        const int lr = f * 16 + li + 48 - 16 * w;
        bf16x8 bb = *(const bf16x8*)&rkLds[swzIdx(lr, chn)];
        r_[f] = __builtin_amdgcn_mfma_f32_16x16x32_bf16(qrf[kc], bb, r_[f], 0, 0, 0);
      }
    }
    // ---- band merge: pre-shuffle (20 bpermute), select locally ----
    float vsh[5][4];
#pragma unroll
    for (int f = 0; f < 5; ++f)
#pragma unroll
      for (int j = 0; j < 4; ++j)
        vsh[f][j] = __shfl(r_[f][j], srcj[j], 64);
    float sv2[4][4];
#pragma unroll
    for (int n = 0; n < 4; ++n)
#pragma unroll
      for (int j = 0; j < 4; ++j)
        sv2[n][j] = c_[n][j] + (cndj[j] ? vsh[n][j] : vsh[n + 1][j]);

    // ---- online softmax: max-reduce + exact defer-rescale ----
    float tmax[4];
    bool grow = false;
#pragma unroll
    for (int j = 0; j < 4; ++j) {
      float t = fmaxf(fmaxf(sv2[0][j], sv2[1][j]), fmaxf(sv2[2][j], sv2[3][j]));
#pragma unroll
      for (int off = 1; off < 16; off <<= 1) t = fmaxf(t, __shfl_xor(t, off, 64));
      tmax[j] = t;
      grow = grow || (t > m_[j]);
    }
    if (__any(grow)) {
      float al[4];
#pragma unroll
      for (int j = 0; j < 4; ++j) {
        const float nm = fmaxf(m_[j], tmax[j]);
        al[j] = __expf(m_[j] - nm);
        m_[j] = nm;
      }
#pragma unroll
      for (int n = 0; n < 4; ++n)
#pragma unroll
        for (int j = 0; j < 4; ++j) o_[n][j] *= al[j];
#pragma unroll
      for (int j = 0; j < 4; ++j) o4[j] *= al[j];
    }
    u16* pw = pLds[w];
#pragma unroll
    for (int n = 0; n < 4; ++n)
#pragma unroll
      for (int j = 0; j < 4; ++j) {
        const float p = __expf(sv2[n][j] - m_[j]);
        const int rw = g * 4 + j, col = n * 16 + li;
        pw[(rw << 6) + ((((col >> 3) ^ (rw & 7)) & 7) << 3) + (col & 7)] = f2bf(p);
      }

    // ---- PV (+ ones column accumulates l into o4) ----
#pragma unroll
    for (int kc = 0; kc < 2; ++kc) {
      const int chn = kc * 4 + g;
      bf16x8 pa = *(const bf16x8*)&pw[swzIdx(li, chn)];
#pragma unroll
      for (int n = 0; n < 4; ++n) {
        bf16x8 vb = *(const bf16x8*)&vtLds[swzIdx(n * 16 + li, chn)];
        o_[n] = __builtin_amdgcn_mfma_f32_16x16x32_bf16(pa, vb, o_[n], 0, 0, 0);
      }
      o4 = __builtin_amdgcn_mfma_f32_16x16x32_bf16(pa, ones, o4, 0, 0, 0);
    }
  }

  float inv[4];
#pragma unroll
  for (int j = 0; j < 4; ++j) inv[j] = 1.f / o4[j];
  u16* obB = ob + (int64_t)b * 524288 + (int64_t)(t0 + w * 16) * 512 + h * 64;
#pragma unroll
  for (int n = 0; n < 4; ++n)
#pragma unroll
    for (int j = 0; j < 4; ++j)
      obB[(int64_t)(g * 4 + j) * 512 + n * 16 + li] = f2bf(o_[n][j] * inv[j]);
}

enum { EPI_BF16 = 0, EPI_BF16_RELU = 1, EPI_F32 = 2, EPI_QKV = 6 };

// C[m,n] = sum_k A[m,k] * Bt[n,k].  Tile 128 x (NW*32).  gld_lds staging.
// K-split use: zA/zB double as per-z element offsets into the K dimension;
// zCbytes routes partials to separate buffers.
template <int EPI, int NW>
__global__ __launch_bounds__(256) void gemm_bt(
    const u16* __restrict__ A, int64_t zA, int lda,
    const u16* __restrict__ Bt, int64_t zB, int ldb,
    char* __restrict__ Cb, int64_t zCbytes, int ldc,
    const float* __restrict__ bias1, int zbias,
    int M, int N, int K)
{
  __shared__ __align__(16) u16 As[128 * BK];
  __shared__ __align__(16) u16 Bs[NW * 32 * BK];

  const int z = blockIdx.z;
  A  += (int64_t)z * zA;
  Bt += (int64_t)z * zB;
  Cb += (int64_t)z * zCbytes;

  const int m0 = blockIdx.y * 128;
  const int n0 = blockIdx.x * (NW * 32);

  const int tid  = threadIdx.x;
  const int lane = tid & 63;
  const int wid  = tid >> 6;
  const int wm = (wid >> 1) * 64;
  const int wn = (wid & 1) * (NW * 16);
  const int fr = lane & 15;
  const int fk = (lane >> 4) * 8;

  f32x4 acc[4][NW];
#pragma unroll
  for (int m = 0; m < 4; ++m)
#pragma unroll
    for (int n = 0; n < NW; ++n) acc[m][n] = (f32x4){0.f, 0.f, 0.f, 0.f};

  for (int kt = 0; kt < K; kt += BK) {
    __syncthreads();
#pragma unroll
    for (int it = 0; it < 4; ++it) {
      const int off = (it * 256 + tid) * 8;
      const int r = off >> 6, c = off & (BK - 1);
      int gr = m0 + r; if (gr > M - 1) gr = M - 1;
      gld16(A + (int64_t)gr * lda + kt + c, &As[off]);
    }
#pragma unroll
    for (int it = 0; it < NW; ++it) {
      const int off = (it * 256 + tid) * 8;
      const int r = off >> 6, c = off & (BK - 1);
      int gr = n0 + r; if (gr > N - 1) gr = N - 1;
      gld16(Bt + (int64_t)gr * ldb + kt + c, &Bs[off]);
    }
    __syncthreads();

#pragma unroll
    for (int kk = 0; kk < BK; kk += 32) {
      bf16x8 af[4], bfv[NW];
#pragma unroll
      for (int m = 0; m < 4; ++m)
        af[m] = *(const bf16x8*)&As[(wm + m * 16 + fr) * BK + kk + fk];
#pragma unroll
      for (int n = 0; n < NW; ++n)
        bfv[n] = *(const bf16x8*)&Bs[(wn + n * 16 + fr) * BK + kk + fk];
#pragma unroll
      for (int m = 0; m < 4; ++m)
#pragma unroll
        for (int n = 0; n < NW; ++n)
          acc[m][n] = __builtin_amdgcn_mfma_f32_16x16x32_bf16(af[m], bfv[n], acc[m][n], 0, 0, 0);
    }
  }

  const int r0 = m0 + wm + (lane >> 4) * 4;
  const int c0 = n0 + wn + fr;
#pragma unroll
  for (int m = 0; m < 4; ++m) {
#pragma unroll
    for (int n = 0; n < NW; ++n) {
      const int col = c0 + n * 16;
      if (col >= N) continue;
      float b1v = 0.f;
      if (EPI == EPI_BF16 || EPI == EPI_BF16_RELU) {
        if (bias1) b1v = bias1[z * zbias + col];
      }
#pragma unroll
      for (int j = 0; j < 4; ++j) {
        const int row = r0 + m * 16 + j;
        if (row >= M) continue;
        const float v = acc[m][n][j];
        if (EPI == EPI_BF16) {
          ((u16*)Cb)[(int64_t)row * ldc + col] = f2bf(v + b1v);
        } else if (EPI == EPI_BF16_RELU) {
          float t = v + b1v; t = t > 0.f ? t : 0.f;
          ((u16*)Cb)[(int64_t)row * ldc + col] = f2bf(t);
        } else if (EPI == EPI_F32) {
          ((float*)Cb)[(int64_t)row * ldc + col] = v;
        } else if (EPI == EPI_QKV) {
          const int which = col >> 9, cc = col & 511;
          const int slot = (which == 0) ? 0 : which + 1;   // 0:qc 2:kb 3:vb
          u16* dst = (u16*)Cb + (int64_t)slot * 2097152 + (int64_t)row * 512 + cc;
          *dst = f2bf(v + bias1[slot * 512 + cc]);
          if (which == 0)                                   // slot 1: qr
            dst[2097152] = f2bf(v + bias1[512 + cc]);
        }
      }
    }
  }
}

// ---------------------------------------------------------------------------
// ALL preprocessing in one dispatch (9474 blocks):
//   [0,4096)      pe sinusoid table
//   [4096,6144)   x -> bf16
//   [6144,6146)   bias combines
//   [6146,9474)   7 weight transposes (fp32 -> bf16 T)
// ---------------------------------------------------------------------------
__global__ __launch_bounds__(256) void prep_all(
    const float* __restrict__ x,
    const float* __restrict__ Wq, const float* __restrict__ Wk,
    const float* __restrict__ Wv, const float* __restrict__ Wo,
    const float* __restrict__ Wr, const float* __restrict__ W1,
    const float* __restrict__ W2,
    const float* __restrict__ bq, const float* __restrict__ cb,
    const float* __restrict__ rb, const float* __restrict__ bk,
    const float* __restrict__ bv, char* __restrict__ wsb)
{
  __shared__ float t[32][33];
  const int bid = blockIdx.x;
  const int tid = threadIdx.x;
  if (bid < 4096) {                       // pe
    u16* pe = (u16*)(wsb + 20480);
    int idx = bid * 256 + tid;
    int i = idx >> 9, j = idx & 511, jf = j & 255;
    float inv = __expf(-(float)jf * (2.0f / 512.0f) * 9.210340371976184f);
    float arg = (float)(i - 1024) * inv;
    pe[idx] = f2bf((j < 256) ? __sinf(arg) : __cosf(arg));
  } else if (bid < 6144) {                // convert x
    u16* xb = (u16*)(wsb + 8933376);
    int idx = (bid - 4096) * 256 + tid;
    f32x4 v = ((const f32x4*)x)[idx];
    u16x4 o;
    o[0] = f2bf(v[0]); o[1] = f2bf(v[1]); o[2] = f2bf(v[2]); o[3] = f2bf(v[3]);
    ((u16x4*)xb)[idx] = o;
  } else if (bid < 6146) {                // biases (bqc|bqr|bkv contiguous)
    int i = (bid - 6144) * 256 + tid;
    float* bqc = (float*)wsb;
    if (i < 512) {
      bqc[i]        = bq[i] + cb[i];
      bqc[512 + i]  = bq[i] + rb[i];
      bqc[1024 + i] = bk[i];
      bqc[1536 + i] = bv[i];
    }
  } else {                                // transposes
    const int tl0 = bid - 6146;
    const float* src; u16* dst;
    int ldi, ldo, bx, by;
    if (tl0 < 1280) {
      const int wsel = tl0 >> 8, tl = tl0 & 255;
      bx = tl & 15; by = tl >> 4; ldi = 512; ldo = 512;
      src = (wsel == 0) ? Wq : (wsel == 1) ? Wk : (wsel == 2) ? Wv
          : (wsel == 3) ? Wo : Wr;
      dst = (u16*)(wsb + 2117632 + (int64_t)wsel * 524288);
    } else if (tl0 < 2304) {
      const int tl = tl0 - 1280;
      bx = tl & 63; by = tl >> 6; ldi = 2048; ldo = 512;
      src = W1; dst = (u16*)(wsb + 4739072);
    } else {
      const int tl = tl0 - 2304;
      bx = tl & 15; by = tl >> 4; ldi = 512; ldo = 2048;
      src = W2; dst = (u16*)(wsb + 6836224);
    }
    const int xx = tid & 31, yy = tid >> 5;   // 32 x 8
    const int r0 = by * 32, c0 = bx * 32;
#pragma unroll
    for (int i = 0; i < 32; i += 8)
      t[yy + i][xx] = src[(int64_t)(r0 + yy + i) * ldi + c0 + xx];
    __syncthreads();
#pragma unroll
    for (int i = 0; i < 32; i += 8)
      dst[(int64_t)(c0 + yy + i) * ldo + r0 + xx] = f2bf(t[xx][yy + i]);
  }
}

// v (b,l,h,dh) bf16 -> vt (b,h,dh,l) bf16;  z = b*8+h
__global__ void transpose_v_kernel(const u16* __restrict__ v, u16* __restrict__ vt) {
  __shared__ u16 t[32][33];
  int z = blockIdx.z;
  const u16* in = v + (int64_t)(z >> 3) * 524288 + (z & 7) * 64;
  u16* out = vt + (int64_t)z * 65536;
  int c0 = blockIdx.x * 32, r0 = blockIdx.y * 32;
  int x = threadIdx.x, y = threadIdx.y;
#pragma unroll
  for (int i = 0; i < 32; i += 8)
    t[y + i][x] = in[(int64_t)(r0 + y + i) * 512 + c0 + x];
  __syncthreads();
#pragma unroll
  for (int i = 0; i < 32; i += 8)
    out[(int64_t)(c0 + y + i) * 1024 + r0 + x] = t[x][y + i];
}

// LN over val = 2*(X1 + X2 + bias).  one wave/row, 4 rows/block, grid(1024).
template <int OUT_F32>
__global__ void layernorm_sum2_kernel(
    const float* __restrict__ X1, const float* __restrict__ X2,
    const float* __restrict__ bias,
    const float* __restrict__ sc, const float* __restrict__ bi,
    void* __restrict__ outv) {
  const int row = blockIdx.x * 4 + (threadIdx.x >> 6);
  const int lane = threadIdx.x & 63;
  const int64_t ro = (int64_t)row * 512;
  f32x4 a1 = ((const f32x4*)(X1 + ro))[lane];
  f32x4 a2 = ((const f32x4*)(X1 + ro))[lane + 64];
  f32x4 b1 = ((const f32x4*)(X2 + ro))[lane];
  f32x4 b2 = ((const f32x4*)(X2 + ro))[lane + 64];
  f32x4 c1 = ((const f32x4*)bias)[lane];
  f32x4 c2 = ((const f32x4*)bias)[lane + 64];
  f32x4 a, b;
#pragma unroll
  for (int e = 0; e < 4; ++e) {
    a[e] = 2.f * (a1[e] + b1[e] + c1[e]);
    b[e] = 2.f * (a2[e] + b2[e] + c2[e]);
  }
  float s = 0.f, q = 0.f;
#pragma unroll
  for (int e = 0; e < 4; ++e) { s += a[e] + b[e]; q += a[e]*a[e] + b[e]*b[e]; }
#pragma unroll
  for (int o = 32; o; o >>= 1) { s += __shfl_xor(s, o, 64); q += __shfl_xor(q, o, 64); }
  const float mu = s * (1.f / 512.f);
  const float var = q * (1.f / 512.f) - mu * mu;
  const float r = rsqrtf(var + 1e-6f);
  const int cc1 = lane * 4, cc2 = (lane + 64) * 4;
  f32x4 s1 = ((const f32x4*)sc)[lane], s2 = ((const f32x4*)sc)[lane + 64];
  f32x4 g1 = ((const f32x4*)bi)[lane], g2 = ((const f32x4*)bi)[lane + 64];
  if (OUT_F32) {
    float* out = (float*)outv;
    f32x4 o1, o2;
#pragma unroll
    for (int e = 0; e < 4; ++e) {
      o1[e] = (a[e] - mu) * r * s1[e] + g1[e];
      o2[e] = (b[e] - mu) * r * s2[e] + g2[e];
    }
    *(f32x4*)&out[ro + cc1] = o1;
    *(f32x4*)&out[ro + cc2] = o2;
  } else {
    u16* out = (u16*)outv;
    u16x4 o1, o2;
#pragma unroll
    for (int e = 0; e < 4; ++e) {
      o1[e] = f2bf((a[e] - mu) * r * s1[e] + g1[e]);
      o2[e] = f2bf((b[e] - mu) * r * s2[e] + g2[e]);
    }
    *(u16x4*)&out[ro + cc1] = o1;
    *(u16x4*)&out[ro + cc2] = o2;
  }
}

// ---------------------------------------------------------------------------
extern "C" void kernel_launch(void* const* d_in, const int* in_sizes, int n_in,
                              void* d_out, int out_size, void* d_ws, size_t ws_size,
                              hipStream_t stream) {
  const float* x    = (const float*)d_in[0];
  const float* Wq   = (const float*)d_in[1];
  const float* bq   = (const float*)d_in[2];
  const float* Wk   = (const float*)d_in[3];
  const float* bk   = (const float*)d_in[4];
  const float* Wv   = (const float*)d_in[5];
  const float* bv   = (const float*)d_in[6];
  const float* cb   = (const float*)d_in[7];
  const float* rb   = (const float*)d_in[8];
  const float* Wr   = (const float*)d_in[9];
  const float* Wo   = (const float*)d_in[10];
  const float* bo   = (const float*)d_in[11];
  const float* ln1s = (const float*)d_in[12];
  const float* ln1b = (const float*)d_in[13];
  const float* W1   = (const float*)d_in[14];
  const float* b1   = (const float*)d_in[15];
  const float* W2   = (const float*)d_in[16];
  const float* b2   = (const float*)d_in[17];
  const float* ln2s = (const float*)d_in[18];
  const float* ln2b = (const float*)d_in[19];
  (void)in_sizes; (void)n_in; (void)out_size; (void)ws_size;

  char* ws = (char*)d_ws;
  float* bqc = (float*)(ws + 0);          // bqc|bqr|bkv contiguous (2048 f32)
  u16* pe  = (u16*)(ws + 20480);          // 2048x512 bf16
  u16* WqT = (u16*)(ws + 2117632);        // Wq|Wk|Wv T contiguous (1536x512)
  u16* WoT = (u16*)(ws + 3690496);
  u16* WrT = (u16*)(ws + 4214784);
  u16* W1T = (u16*)(ws + 4739072);        // 2048x512
  u16* W2T = (u16*)(ws + 6836224);        // 512x2048
  u16* xb  = (u16*)(ws + 8933376);        // 4096x512 bf16
  u16* qc  = (u16*)(ws + 13127680);       // qc|qr|kb|vb each +2097152 u16
  u16* kb  = (u16*)(ws + 21516288);
  u16* vb  = (u16*)(ws + 25710592);
  u16* vt  = (u16*)(ws + 29904896);       // (b,h,dh,l)
  u16* rk  = (u16*)(ws + 34099200);       // 2048x512
  u16* ob  = (u16*)(ws + 36196352);       // 4096x512 (attn out)
  char* scratch = ws + 40390656;
  // K-split partial buffers: part A in scratch, part B over dead qc|qr (8MB)
  float* pA  = (float*)scratch;                   // 4096x512 fp32
  float* pB  = (float*)(ws + 13127680);           // qc region (dead post-attn)
  u16*   ln1 = (u16*)(scratch + 8388608);         // 4096x512 bf16
  u16*   ffn1= (u16*)(scratch + 12582912);        // 4096x2048 bf16
  const int64_t zPart = (int64_t)((char*)pB - (char*)pA);

  const dim3 blk(256), tb(32, 8);

  prep_all<<<dim3(9474), blk, 0, stream>>>(x, Wq, Wk, Wv, Wo, Wr, W1, W2,
                                           bq, cb, rb, bk, bv, ws);

  // fused q/qr/k/v projection (N = 1536 over WqT|WkT|WvT)
  gemm_bt<EPI_QKV, 2><<<dim3(24, 32, 1), blk, 0, stream>>>(
      xb, 0, 512, WqT, 0, 512, (char*)qc, 0, 512, bqc, 0, 4096, 1536, 512);
  gemm_bt<EPI_BF16, 2><<<dim3(8, 16, 1), blk, 0, stream>>>(
      pe, 0, 512, WrT, 0, 512, (char*)rk, 0, 512, nullptr, 0, 2048, 512, 512);
  transpose_v_kernel<<<dim3(2, 32, 32), tb, 0, stream>>>(vb, vt);

  // fused attention (XCD-aware 1-D grid)
  fused_attn_kernel<<<dim3(512), blk, 0, stream>>>(qc, qc + 2097152, kb, vt, rk, ob);

  // o@Wo, K-split z=2 -> partials; LN1 folds +bo, x2, sum
  gemm_bt<EPI_F32, 2><<<dim3(8, 32, 2), blk, 0, stream>>>(
      ob, 256, 512, WoT, 256, 512, (char*)pA, zPart, 512, nullptr, 0,
      4096, 512, 256);
  layernorm_sum2_kernel<0><<<dim3(1024), blk, 0, stream>>>(
      pA, pB, bo, ln1s, ln1b, ln1);
  // FFN
  gemm_bt<EPI_BF16_RELU, 4><<<dim3(16, 32, 1), blk, 0, stream>>>(
      ln1, 0, 512, W1T, 0, 512, (char*)ffn1, 0, 2048, b1, 0, 4096, 2048, 512);
  gemm_bt<EPI_F32, 2><<<dim3(8, 32, 2), blk, 0, stream>>>(
      ffn1, 1024, 2048, W2T, 1024, 2048, (char*)pA, zPart, 512, nullptr, 0,
      4096, 512, 1024);
  layernorm_sum2_kernel<1><<<dim3(1024), blk, 0, stream>>>(
      pA, pB, b2, ln2s, ln2b, d_out);
}

// Round 9
// 157.645 us; speedup vs baseline: 3.8599x; 1.0385x over previous
//
#include <hip/hip_runtime.h>
#include <stdint.h>

// ---------------------------------------------------------------------------
// TransformerXL encoder layer.  Inputs fp32, OUTPUT fp32.  b=4 l=1024 d=512
// h=8 dh=64.
// Round 9: gemm_bt rotated to double-buffered 2-phase (STAGE(next) before
// compute(cur), one vmcnt-draining barrier per K-step) -- same fix attn got
// in round 7.  Everything else byte-identical to round 8.
// rel shift closed form: shifted[t,j] = R[t, 1024 + j - t],  R = (q+rb)@rk^T.
// ---------------------------------------------------------------------------

typedef unsigned short u16;
typedef __attribute__((ext_vector_type(8))) __bf16 bf16x8;
typedef __attribute__((ext_vector_type(8))) unsigned short u16x8;
typedef __attribute__((ext_vector_type(4))) float f32x4;
typedef __attribute__((ext_vector_type(4))) unsigned short u16x4;

#define BK 64

static __device__ __forceinline__ u16 f2bf(float f) {
  union { float f; unsigned int i; } v; v.f = f;
  unsigned int r = v.i + 0x7FFFu + ((v.i >> 16) & 1u);
  return (u16)(r >> 16);
}

// global->LDS direct copy, 16B per lane (lds dest must be linear in lane id).
static __device__ __forceinline__ void gld16(const void* g, void* l) {
  __builtin_amdgcn_global_load_lds(
      (__attribute__((address_space(1))) void*)(uintptr_t)g,
      (__attribute__((address_space(3))) void*)(uintptr_t)l,
      16, 0, 0);
}

// swizzled u16 index into a [rows][64]-u16 LDS tile (16B chunk ^= row&7).
static __device__ __forceinline__ int swzIdx(int r, int ch) {
  return (r << 6) + (((ch ^ (r & 7)) & 7) << 3);
}

// ---------------------------------------------------------------------------
// Fused attention (unchanged from round 8).  512 blocks, XCD = bid&7 = head.
// ---------------------------------------------------------------------------
__global__ __launch_bounds__(256) void fused_attn_kernel(
    const u16* __restrict__ qc, const u16* __restrict__ qr,
    const u16* __restrict__ kb, const u16* __restrict__ vt,
    const u16* __restrict__ rk, u16* __restrict__ ob)
{
  __shared__ __align__(16) u16 kbLds[64 * 64];    // k tile  [j][d]
  __shared__ __align__(16) u16 vtLds[64 * 64];    // vt tile [c][j]
  __shared__ __align__(16) u16 rkLds[128 * 64];   // rk band [lr][d]
  __shared__ __align__(16) u16 pLds[4][16 * 64];  // per-wave P [ttw][j]

  const int tid  = threadIdx.x;
  const int lane = tid & 63;
  const int w    = tid >> 6;
  const int g    = lane >> 4;
  const int li   = lane & 15;

  const int bid = blockIdx.x;          // XCD = bid&7 = h
  const int h   = bid & 7;
  const int s   = bid >> 3;
  const int t0  = (s & 15) * 64;
  const int b   = s >> 4;

  const int64_t qoff = (int64_t)b * 524288 + (int64_t)(t0 + w * 16 + li) * 512
                     + h * 64 + g * 8;
  bf16x8 qcf[2], qrf[2];
  qcf[0] = *(const bf16x8*)(qc + qoff);
  qcf[1] = *(const bf16x8*)(qc + qoff + 32);
  qrf[0] = *(const bf16x8*)(qr + qoff);
  qrf[1] = *(const bf16x8*)(qr + qoff + 32);

  const u16* kbB = kb + (int64_t)b * 524288 + h * 64;
  const u16* vtB = vt + (int64_t)(b * 8 + h) * 65536;
  const u16* rkB = rk + h * 64;

  bf16x8 ones;
#pragma unroll
  for (int e = 0; e < 8; ++e) ((u16*)&ones)[e] = 0x3F80;

  float m_[4] = {-1e30f, -1e30f, -1e30f, -1e30f};
  f32x4 o_[4];
  f32x4 o4 = (f32x4){0.f, 0.f, 0.f, 0.f};        // row-sum accumulator (= l)
#pragma unroll
  for (int n = 0; n < 4; ++n) o_[n] = (f32x4){0.f, 0.f, 0.f, 0.f};

  const int base = li - 4 * g + 15;            // in [3,30]
  int  srcj[4];
  bool cndj[4];
#pragma unroll
  for (int j = 0; j < 4; ++j) {
    srcj[j] = ((base - j) & 15) | (lane & 48);
    cndj[j] = (base - j) < 16;
  }

  u16x8 sk[2], svv[2], srr[4];
  auto ISSUE = [&](int itx) {
    const int j0 = itx * 64;
    const int ub = 1024 + j0 - t0 - 63;        // >= 1
#pragma unroll
    for (int p = 0; p < 2; ++p) {
      const int flat = p * 256 + tid, r = flat >> 3, ch = flat & 7;
      sk[p]  = *(const u16x8*)(kbB + (int64_t)(j0 + r) * 512 + ch * 8);
      svv[p] = *(const u16x8*)(vtB + (int64_t)r * 1024 + j0 + ch * 8);
    }
#pragma unroll
    for (int p = 0; p < 4; ++p) {
      const int flat = p * 256 + tid, r = flat >> 3, ch = flat & 7;
      int u = ub + r; u = u < 2047 ? u : 2047;
      srr[p] = *(const u16x8*)(rkB + (int64_t)u * 512 + ch * 8);
    }
  };

  ISSUE(0);
  for (int it = 0; it < 16; ++it) {
    __syncthreads();
#pragma unroll
    for (int p = 0; p < 2; ++p) {
      const int flat = p * 256 + tid, r = flat >> 3, ch = flat & 7;
      *(u16x8*)&kbLds[swzIdx(r, ch)] = sk[p];
      *(u16x8*)&vtLds[swzIdx(r, ch)] = svv[p];
    }
#pragma unroll
    for (int p = 0; p < 4; ++p) {
      const int flat = p * 256 + tid, r = flat >> 3, ch = flat & 7;
      *(u16x8*)&rkLds[swzIdx(r, ch)] = srr[p];
    }
    __syncthreads();
    if (it < 15) ISSUE(it + 1);

    // ---- content logits ----
    f32x4 c_[4];
#pragma unroll
    for (int n = 0; n < 4; ++n) c_[n] = (f32x4){0.f, 0.f, 0.f, 0.f};
#pragma unroll
    for (int kc = 0; kc < 2; ++kc) {
      const int chn = kc * 4 + g;
#pragma unroll
      for (int n = 0; n < 4; ++n) {
        bf16x8 bb = *(const bf16x8*)&kbLds[swzIdx(n * 16 + li, chn)];
        c_[n] = __builtin_amdgcn_mfma_f32_16x16x32_bf16(qcf[kc], bb, c_[n], 0, 0, 0);
      }
    }
    // ---- rel band ----
    f32x4 r_[5];
#pragma unroll
    for (int f = 0; f < 5; ++f) r_[f] = (f32x4){0.f, 0.f, 0.f, 0.f};
#pragma unroll
    for (int kc = 0; kc < 2; ++kc) {
      const int chn = kc * 4 + g;
#pragma unroll
      for (int f = 0; f < 5; ++f) {
        const int lr = f * 16 + li + 48 - 16 * w;
        bf16x8 bb = *(const bf16x8*)&rkLds[swzIdx(lr, chn)];
        r_[f] = __builtin_amdgcn_mfma_f32_16x16x32_bf16(qrf[kc], bb, r_[f], 0, 0, 0);
      }
    }
    // ---- band merge: 20 bpermutes + local select ----
    float vsh[5][4];
#pragma unroll
    for (int f = 0; f < 5; ++f)
#pragma unroll
      for (int j = 0; j < 4; ++j)
        vsh[f][j] = __shfl(r_[f][j], srcj[j], 64);
    float sv2[4][4];
#pragma unroll
    for (int n = 0; n < 4; ++n)
#pragma unroll
      for (int j = 0; j < 4; ++j)
        sv2[n][j] = c_[n][j] + (cndj[j] ? vsh[n][j] : vsh[n + 1][j]);

    // ---- online softmax: max-reduce + exact defer-rescale ----
    float tmax[4];
    bool grow = false;
#pragma unroll
    for (int j = 0; j < 4; ++j) {
      float t = fmaxf(fmaxf(sv2[0][j], sv2[1][j]), fmaxf(sv2[2][j], sv2[3][j]));
#pragma unroll
      for (int off = 1; off < 16; off <<= 1) t = fmaxf(t, __shfl_xor(t, off, 64));
      tmax[j] = t;
      grow = grow || (t > m_[j]);
    }
    if (__any(grow)) {
      float al[4];
#pragma unroll
      for (int j = 0; j < 4; ++j) {
        const float nm = fmaxf(m_[j], tmax[j]);
        al[j] = __expf(m_[j] - nm);
        m_[j] = nm;
      }
#pragma unroll
      for (int n = 0; n < 4; ++n)
#pragma unroll
        for (int j = 0; j < 4; ++j) o_[n][j] *= al[j];
#pragma unroll
      for (int j = 0; j < 4; ++j) o4[j] *= al[j];
    }
    u16* pw = pLds[w];
#pragma unroll
    for (int n = 0; n < 4; ++n)
#pragma unroll
      for (int j = 0; j < 4; ++j) {
        const float p = __expf(sv2[n][j] - m_[j]);
        const int rw = g * 4 + j, col = n * 16 + li;
        pw[(rw << 6) + ((((col >> 3) ^ (rw & 7)) & 7) << 3) + (col & 7)] = f2bf(p);
      }

    // ---- PV (+ ones column accumulates l) ----
#pragma unroll
    for (int kc = 0; kc < 2; ++kc) {
      const int chn = kc * 4 + g;
      bf16x8 pa = *(const bf16x8*)&pw[swzIdx(li, chn)];
#pragma unroll
      for (int n = 0; n < 4; ++n) {
        bf16x8 vb = *(const bf16x8*)&vtLds[swzIdx(n * 16 + li, chn)];
        o_[n] = __builtin_amdgcn_mfma_f32_16x16x32_bf16(pa, vb, o_[n], 0, 0, 0);
      }
      o4 = __builtin_amdgcn_mfma_f32_16x16x32_bf16(pa, ones, o4, 0, 0, 0);
    }
  }

  float inv[4];
#pragma unroll
  for (int j = 0; j < 4; ++j) inv[j] = 1.f / o4[j];
  u16* obB = ob + (int64_t)b * 524288 + (int64_t)(t0 + w * 16) * 512 + h * 64;
#pragma unroll
  for (int n = 0; n < 4; ++n)
#pragma unroll
    for (int j = 0; j < 4; ++j)
      obB[(int64_t)(g * 4 + j) * 512 + n * 16 + li] = f2bf(o_[n][j] * inv[j]);
}

enum { EPI_BF16 = 0, EPI_BF16_RELU = 1, EPI_F32 = 2, EPI_QKV = 6 };

// C[m,n] = sum_k A[m,k] * Bt[n,k].  Tile 128 x (NW*32).  gld_lds staging,
// ROTATED double-buffered 2-phase: STAGE(s+1) issued before compute(s); the
// single per-step barrier drains vmcnt AFTER a full compute phase.
template <int EPI, int NW>
__global__ __launch_bounds__(256) void gemm_bt(
    const u16* __restrict__ A, int64_t zA, int lda,
    const u16* __restrict__ Bt, int64_t zB, int ldb,
    char* __restrict__ Cb, int64_t zCbytes, int ldc,
    const float* __restrict__ bias1, int zbias,
    int M, int N, int K)
{
  __shared__ __align__(16) u16 As[2][128 * BK];
  __shared__ __align__(16) u16 Bs[2][NW * 32 * BK];

  const int z = blockIdx.z;
  A  += (int64_t)z * zA;
  Bt += (int64_t)z * zB;
  Cb += (int64_t)z * zCbytes;

  const int m0 = blockIdx.y * 128;
  const int n0 = blockIdx.x * (NW * 32);

  const int tid  = threadIdx.x;
  const int lane = tid & 63;
  const int wid  = tid >> 6;
  const int wm = (wid >> 1) * 64;
  const int wn = (wid & 1) * (NW * 16);
  const int fr = lane & 15;
  const int fk = (lane >> 4) * 8;

  f32x4 acc[4][NW];
#pragma unroll
  for (int m = 0; m < 4; ++m)
#pragma unroll
    for (int n = 0; n < NW; ++n) acc[m][n] = (f32x4){0.f, 0.f, 0.f, 0.f};

  const int nsteps = K >> 6;   // K / BK
  auto STAGE = [&](int step, int buf) {
    const int kt = step * BK;
#pragma unroll
    for (int it = 0; it < 4; ++it) {
      const int off = (it * 256 + tid) * 8;
      const int r = off >> 6, c = off & (BK - 1);
      int gr = m0 + r; if (gr > M - 1) gr = M - 1;
      gld16(A + (int64_t)gr * lda + kt + c, &As[buf][off]);
    }
#pragma unroll
    for (int it = 0; it < NW; ++it) {
      const int off = (it * 256 + tid) * 8;
      const int r = off >> 6, c = off & (BK - 1);
      int gr = n0 + r; if (gr > N - 1) gr = N - 1;
      gld16(Bt + (int64_t)gr * ldb + kt + c, &Bs[buf][off]);
    }
  };

  STAGE(0, 0);
  for (int s = 0; s < nsteps; ++s) {
    const int cur = s & 1;
    __syncthreads();   // drains vmcnt: buf[cur] ready; prev compute's reads done
    if (s + 1 < nsteps) STAGE(s + 1, cur ^ 1);   // flies under compute below

#pragma unroll
    for (int kk = 0; kk < BK; kk += 32) {
      bf16x8 af[4], bfv[NW];
#pragma unroll
      for (int m = 0; m < 4; ++m)
        af[m] = *(const bf16x8*)&As[cur][(wm + m * 16 + fr) * BK + kk + fk];
#pragma unroll
      for (int n = 0; n < NW; ++n)
        bfv[n] = *(const bf16x8*)&Bs[cur][(wn + n * 16 + fr) * BK + kk + fk];
#pragma unroll
      for (int m = 0; m < 4; ++m)
#pragma unroll
        for (int n = 0; n < NW; ++n)
          acc[m][n] = __builtin_amdgcn_mfma_f32_16x16x32_bf16(af[m], bfv[n], acc[m][n], 0, 0, 0);
    }
  }

  const int r0 = m0 + wm + (lane >> 4) * 4;
  const int c0 = n0 + wn + fr;
#pragma unroll
  for (int m = 0; m < 4; ++m) {
#pragma unroll
    for (int n = 0; n < NW; ++n) {
      const int col = c0 + n * 16;
      if (col >= N) continue;
      float b1v = 0.f;
      if (EPI == EPI_BF16 || EPI == EPI_BF16_RELU) {
        if (bias1) b1v = bias1[z * zbias + col];
      }
#pragma unroll
      for (int j = 0; j < 4; ++j) {
        const int row = r0 + m * 16 + j;
        if (row >= M) continue;
        const float v = acc[m][n][j];
        if (EPI == EPI_BF16) {
          ((u16*)Cb)[(int64_t)row * ldc + col] = f2bf(v + b1v);
        } else if (EPI == EPI_BF16_RELU) {
          float t = v + b1v; t = t > 0.f ? t : 0.f;
          ((u16*)Cb)[(int64_t)row * ldc + col] = f2bf(t);
        } else if (EPI == EPI_F32) {
          ((float*)Cb)[(int64_t)row * ldc + col] = v;
        } else if (EPI == EPI_QKV) {
          const int which = col >> 9, cc = col & 511;
          const int slot = (which == 0) ? 0 : which + 1;   // 0:qc 2:kb 3:vb
          u16* dst = (u16*)Cb + (int64_t)slot * 2097152 + (int64_t)row * 512 + cc;
          *dst = f2bf(v + bias1[slot * 512 + cc]);
          if (which == 0)                                   // slot 1: qr
            dst[2097152] = f2bf(v + bias1[512 + cc]);
        }
      }
    }
  }
}

// ---------------------------------------------------------------------------
// ALL preprocessing in one dispatch (9474 blocks).
// ---------------------------------------------------------------------------
__global__ __launch_bounds__(256) void prep_all(
    const float* __restrict__ x,
    const float* __restrict__ Wq, const float* __restrict__ Wk,
    const float* __restrict__ Wv, const float* __restrict__ Wo,
    const float* __restrict__ Wr, const float* __restrict__ W1,
    const float* __restrict__ W2,
    const float* __restrict__ bq, const float* __restrict__ cb,
    const float* __restrict__ rb, const float* __restrict__ bk,
    const float* __restrict__ bv, char* __restrict__ wsb)
{
  __shared__ float t[32][33];
  const int bid = blockIdx.x;
  const int tid = threadIdx.x;
  if (bid < 4096) {                       // pe
    u16* pe = (u16*)(wsb + 20480);
    int idx = bid * 256 + tid;
    int i = idx >> 9, j = idx & 511, jf = j & 255;
    float inv = __expf(-(float)jf * (2.0f / 512.0f) * 9.210340371976184f);
    float arg = (float)(i - 1024) * inv;
    pe[idx] = f2bf((j < 256) ? __sinf(arg) : __cosf(arg));
  } else if (bid < 6144) {                // convert x
    u16* xb = (u16*)(wsb + 8933376);
    int idx = (bid - 4096) * 256 + tid;
    f32x4 v = ((const f32x4*)x)[idx];
    u16x4 o;
    o[0] = f2bf(v[0]); o[1] = f2bf(v[1]); o[2] = f2bf(v[2]); o[3] = f2bf(v[3]);
    ((u16x4*)xb)[idx] = o;
  } else if (bid < 6146) {                // biases (bqc|bqr|bkv contiguous)
    int i = (bid - 6144) * 256 + tid;
    float* bqc = (float*)wsb;
    if (i < 512) {
      bqc[i]        = bq[i] + cb[i];
      bqc[512 + i]  = bq[i] + rb[i];
      bqc[1024 + i] = bk[i];
      bqc[1536 + i] = bv[i];
    }
  } else {                                // transposes
    const int tl0 = bid - 6146;
    const float* src; u16* dst;
    int ldi, ldo, bx, by;
    if (tl0 < 1280) {
      const int wsel = tl0 >> 8, tl = tl0 & 255;
      bx = tl & 15; by = tl >> 4; ldi = 512; ldo = 512;
      src = (wsel == 0) ? Wq : (wsel == 1) ? Wk : (wsel == 2) ? Wv
          : (wsel == 3) ? Wo : Wr;
      dst = (u16*)(wsb + 2117632 + (int64_t)wsel * 524288);
    } else if (tl0 < 2304) {
      const int tl = tl0 - 1280;
      bx = tl & 63; by = tl >> 6; ldi = 2048; ldo = 512;
      src = W1; dst = (u16*)(wsb + 4739072);
    } else {
      const int tl = tl0 - 2304;
      bx = tl & 15; by = tl >> 4; ldi = 512; ldo = 2048;
      src = W2; dst = (u16*)(wsb + 6836224);
    }
    const int xx = tid & 31, yy = tid >> 5;   // 32 x 8
    const int r0 = by * 32, c0 = bx * 32;
#pragma unroll
    for (int i = 0; i < 32; i += 8)
      t[yy + i][xx] = src[(int64_t)(r0 + yy + i) * ldi + c0 + xx];
    __syncthreads();
#pragma unroll
    for (int i = 0; i < 32; i += 8)
      dst[(int64_t)(c0 + yy + i) * ldo + r0 + xx] = f2bf(t[xx][yy + i]);
  }
}

// v (b,l,h,dh) bf16 -> vt (b,h,dh,l) bf16;  z = b*8+h
__global__ void transpose_v_kernel(const u16* __restrict__ v, u16* __restrict__ vt) {
  __shared__ u16 t[32][33];
  int z = blockIdx.z;
  const u16* in = v + (int64_t)(z >> 3) * 524288 + (z & 7) * 64;
  u16* out = vt + (int64_t)z * 65536;
  int c0 = blockIdx.x * 32, r0 = blockIdx.y * 32;
  int x = threadIdx.x, y = threadIdx.y;
#pragma unroll
  for (int i = 0; i < 32; i += 8)
    t[y + i][x] = in[(int64_t)(r0 + y + i) * 512 + c0 + x];
  __syncthreads();
#pragma unroll
  for (int i = 0; i < 32; i += 8)
    out[(int64_t)(c0 + y + i) * 1024 + r0 + x] = t[x][y + i];
}

// LN over val = 2*(X1 + X2 + bias).  one wave/row, 4 rows/block, grid(1024).
template <int OUT_F32>
__global__ void layernorm_sum2_kernel(
    const float* __restrict__ X1, const float* __restrict__ X2,
    const float* __restrict__ bias,
    const float* __restrict__ sc, const float* __restrict__ bi,
    void* __restrict__ outv) {
  const int row = blockIdx.x * 4 + (threadIdx.x >> 6);
  const int lane = threadIdx.x & 63;
  const int64_t ro = (int64_t)row * 512;
  f32x4 a1 = ((const f32x4*)(X1 + ro))[lane];
  f32x4 a2 = ((const f32x4*)(X1 + ro))[lane + 64];
  f32x4 b1 = ((const f32x4*)(X2 + ro))[lane];
  f32x4 b2 = ((const f32x4*)(X2 + ro))[lane + 64];
  f32x4 c1 = ((const f32x4*)bias)[lane];
  f32x4 c2 = ((const f32x4*)bias)[lane + 64];
  f32x4 a, b;
#pragma unroll
  for (int e = 0; e < 4; ++e) {
    a[e] = 2.f * (a1[e] + b1[e] + c1[e]);
    b[e] = 2.f * (a2[e] + b2[e] + c2[e]);
  }
  float s = 0.f, q = 0.f;
#pragma unroll
  for (int e = 0; e < 4; ++e) { s += a[e] + b[e]; q += a[e]*a[e] + b[e]*b[e]; }
#pragma unroll
  for (int o = 32; o; o >>= 1) { s += __shfl_xor(s, o, 64); q += __shfl_xor(q, o, 64); }
  const float mu = s * (1.f / 512.f);
  const float var = q * (1.f / 512.f) - mu * mu;
  const float r = rsqrtf(var + 1e-6f);
  const int cc1 = lane * 4, cc2 = (lane + 64) * 4;
  f32x4 s1 = ((const f32x4*)sc)[lane], s2 = ((const f32x4*)sc)[lane + 64];
  f32x4 g1 = ((const f32x4*)bi)[lane], g2 = ((const f32x4*)bi)[lane + 64];
  if (OUT_F32) {
    float* out = (float*)outv;
    f32x4 o1, o2;
#pragma unroll
    for (int e = 0; e < 4; ++e) {
      o1[e] = (a[e] - mu) * r * s1[e] + g1[e];
      o2[e] = (b[e] - mu) * r * s2[e] + g2[e];
    }
    *(f32x4*)&out[ro + cc1] = o1;
    *(f32x4*)&out[ro + cc2] = o2;
  } else {
    u16* out = (u16*)outv;
    u16x4 o1, o2;
#pragma unroll
    for (int e = 0; e < 4; ++e) {
      o1[e] = f2bf((a[e] - mu) * r * s1[e] + g1[e]);
      o2[e] = f2bf((b[e] - mu) * r * s2[e] + g2[e]);
    }
    *(u16x4*)&out[ro + cc1] = o1;
    *(u16x4*)&out[ro + cc2] = o2;
  }
}

// ---------------------------------------------------------------------------
extern "C" void kernel_launch(void* const* d_in, const int* in_sizes, int n_in,
                              void* d_out, int out_size, void* d_ws, size_t ws_size,
                              hipStream_t stream) {
  const float* x    = (const float*)d_in[0];
  const float* Wq   = (const float*)d_in[1];
  const float* bq   = (const float*)d_in[2];
  const float* Wk   = (const float*)d_in[3];
  const float* bk   = (const float*)d_in[4];
  const float* Wv   = (const float*)d_in[5];
  const float* bv   = (const float*)d_in[6];
  const float* cb   = (const float*)d_in[7];
  const float* rb   = (const float*)d_in[8];
  const float* Wr   = (const float*)d_in[9];
  const float* Wo   = (const float*)d_in[10];
  const float* bo   = (const float*)d_in[11];
  const float* ln1s = (const float*)d_in[12];
  const float* ln1b = (const float*)d_in[13];
  const float* W1   = (const float*)d_in[14];
  const float* b1   = (const float*)d_in[15];
  const float* W2   = (const float*)d_in[16];
  const float* b2   = (const float*)d_in[17];
  const float* ln2s = (const float*)d_in[18];
  const float* ln2b = (const float*)d_in[19];
  (void)in_sizes; (void)n_in; (void)out_size; (void)ws_size;

  char* ws = (char*)d_ws;
  float* bqc = (float*)(ws + 0);          // bqc|bqr|bkv contiguous (2048 f32)
  u16* pe  = (u16*)(ws + 20480);          // 2048x512 bf16
  u16* WqT = (u16*)(ws + 2117632);        // Wq|Wk|Wv T contiguous (1536x512)
  u16* WoT = (u16*)(ws + 3690496);
  u16* WrT = (u16*)(ws + 4214784);
  u16* W1T = (u16*)(ws + 4739072);        // 2048x512
  u16* W2T = (u16*)(ws + 6836224);        // 512x2048
  u16* xb  = (u16*)(ws + 8933376);        // 4096x512 bf16
  u16* qc  = (u16*)(ws + 13127680);       // qc|qr|kb|vb each +2097152 u16
  u16* kb  = (u16*)(ws + 21516288);
  u16* vb  = (u16*)(ws + 25710592);
  u16* vt  = (u16*)(ws + 29904896);       // (b,h,dh,l)
  u16* rk  = (u16*)(ws + 34099200);       // 2048x512
  u16* ob  = (u16*)(ws + 36196352);       // 4096x512 (attn out)
  char* scratch = ws + 40390656;
  float* pA  = (float*)scratch;                   // 4096x512 fp32
  float* pB  = (float*)(ws + 13127680);           // qc region (dead post-attn)
  u16*   ln1 = (u16*)(scratch + 8388608);         // 4096x512 bf16
  u16*   ffn1= (u16*)(scratch + 12582912);        // 4096x2048 bf16
  const int64_t zPart = (int64_t)((char*)pB - (char*)pA);

  const dim3 blk(256), tb(32, 8);

  prep_all<<<dim3(9474), blk, 0, stream>>>(x, Wq, Wk, Wv, Wo, Wr, W1, W2,
                                           bq, cb, rb, bk, bv, ws);

  // fused q/qr/k/v projection (N = 1536 over WqT|WkT|WvT)
  gemm_bt<EPI_QKV, 2><<<dim3(24, 32, 1), blk, 0, stream>>>(
      xb, 0, 512, WqT, 0, 512, (char*)qc, 0, 512, bqc, 0, 4096, 1536, 512);
  gemm_bt<EPI_BF16, 2><<<dim3(8, 16, 1), blk, 0, stream>>>(
      pe, 0, 512, WrT, 0, 512, (char*)rk, 0, 512, nullptr, 0, 2048, 512, 512);
  transpose_v_kernel<<<dim3(2, 32, 32), tb, 0, stream>>>(vb, vt);

  // fused attention (XCD-aware 1-D grid)
  fused_attn_kernel<<<dim3(512), blk, 0, stream>>>(qc, qc + 2097152, kb, vt, rk, ob);

  // o@Wo, K-split z=2 -> partials; LN1 folds +bo, x2, sum
  gemm_bt<EPI_F32, 2><<<dim3(8, 32, 2), blk, 0, stream>>>(
      ob, 256, 512, WoT, 256, 512, (char*)pA, zPart, 512, nullptr, 0,
      4096, 512, 256);
  layernorm_sum2_kernel<0><<<dim3(1024), blk, 0, stream>>>(
      pA, pB, bo, ln1s, ln1b, ln1);
  // FFN
  gemm_bt<EPI_BF16_RELU, 4><<<dim3(16, 32, 1), blk, 0, stream>>>(
      ln1, 0, 512, W1T, 0, 512, (char*)ffn1, 0, 2048, b1, 0, 4096, 2048, 512);
  gemm_bt<EPI_F32, 2><<<dim3(8, 32, 2), blk, 0, stream>>>(
      ffn1, 1024, 2048, W2T, 1024, 2048, (char*)pA, zPart, 512, nullptr, 0,
      4096, 512, 1024);
  layernorm_sum2_kernel<1><<<dim3(1024), blk, 0, stream>>>(
      pA, pB, b2, ln2s, ln2b, d_out);
}

// Round 10
// 143.801 us; speedup vs baseline: 4.2315x; 1.0963x over previous
//
#include <hip/hip_runtime.h>
#include <stdint.h>

// ---------------------------------------------------------------------------
// TransformerXL encoder layer.  Inputs fp32, OUTPUT fp32.  b=4 l=1024 d=512
// h=8 dh=64.
// Round 10: attn occupancy x2 — 512-thread blocks pair two 64-row q-tiles
// that share the SAME kv tiles (kb/vt LDS + staging shared; rk band + pLds
// per half).  Grid 256, 16 waves/CU.  Bitwise-identical per-row math.
// Also: rk GEMM merged into the QKV dispatch (896-block 1-D decode).
// rel shift closed form: shifted[t,j] = R[t, 1024 + j - t],  R = (q+rb)@rk^T.
// ---------------------------------------------------------------------------

typedef unsigned short u16;
typedef __attribute__((ext_vector_type(8))) __bf16 bf16x8;
typedef __attribute__((ext_vector_type(8))) unsigned short u16x8;
typedef __attribute__((ext_vector_type(4))) float f32x4;
typedef __attribute__((ext_vector_type(4))) unsigned short u16x4;

#define BK 64

static __device__ __forceinline__ u16 f2bf(float f) {
  union { float f; unsigned int i; } v; v.f = f;
  unsigned int r = v.i + 0x7FFFu + ((v.i >> 16) & 1u);
  return (u16)(r >> 16);
}

// global->LDS direct copy, 16B per lane (lds dest must be linear in lane id).
static __device__ __forceinline__ void gld16(const void* g, void* l) {
  __builtin_amdgcn_global_load_lds(
      (__attribute__((address_space(1))) void*)(uintptr_t)g,
      (__attribute__((address_space(3))) void*)(uintptr_t)l,
      16, 0, 0);
}

// swizzled u16 index into a [rows][64]-u16 LDS tile (16B chunk ^= row&7).
static __device__ __forceinline__ int swzIdx(int r, int ch) {
  return (r << 6) + (((ch ^ (r & 7)) & 7) << 3);
}

// ---------------------------------------------------------------------------
// Fused attention.  256 blocks x 512 threads.  bid: h = bid&7 (XCD), s=bid>>3:
// qt = s&7, b = s>>3.  Waves 0-3 own q-rows [qt*128, +64), waves 4-7 the next
// 64.  Both halves consume the SAME kv tile -> kb/vt LDS shared.
// ---------------------------------------------------------------------------
__global__ __launch_bounds__(512) void fused_attn_kernel(
    const u16* __restrict__ qc, const u16* __restrict__ qr,
    const u16* __restrict__ kb, const u16* __restrict__ vt,
    const u16* __restrict__ rk, u16* __restrict__ ob)
{
  __shared__ __align__(16) u16 kbLds[64 * 64];       // k tile  [j][d] (shared)
  __shared__ __align__(16) u16 vtLds[64 * 64];       // vt tile [c][j] (shared)
  __shared__ __align__(16) u16 rkLds[2][128 * 64];   // rk band per half
  __shared__ __align__(16) u16 pLds[8][16 * 64];     // per-wave P

  const int tid  = threadIdx.x;
  const int lane = tid & 63;
  const int w    = tid >> 6;          // 0..7
  const int th   = w >> 2;            // q-tile half
  const int wl   = w & 3;             // wave within half
  const int g    = lane >> 4;
  const int li   = lane & 15;

  const int bid = blockIdx.x;         // XCD = bid&7 = h
  const int h   = bid & 7;
  const int s   = bid >> 3;
  const int qt  = s & 7;
  const int b   = s >> 3;
  const int t0  = qt * 128 + th * 64; // this half's q-tile base

  const int64_t qoff = (int64_t)b * 524288 + (int64_t)(t0 + wl * 16 + li) * 512
                     + h * 64 + g * 8;
  bf16x8 qcf[2], qrf[2];
  qcf[0] = *(const bf16x8*)(qc + qoff);
  qcf[1] = *(const bf16x8*)(qc + qoff + 32);
  qrf[0] = *(const bf16x8*)(qr + qoff);
  qrf[1] = *(const bf16x8*)(qr + qoff + 32);

  const u16* kbB = kb + (int64_t)b * 524288 + h * 64;
  const u16* vtB = vt + (int64_t)(b * 8 + h) * 65536;
  const u16* rkB = rk + h * 64;

  bf16x8 ones;
#pragma unroll
  for (int e = 0; e < 8; ++e) ((u16*)&ones)[e] = 0x3F80;

  float m_[4] = {-1e30f, -1e30f, -1e30f, -1e30f};
  f32x4 o_[4];
  f32x4 o4 = (f32x4){0.f, 0.f, 0.f, 0.f};        // row-sum accumulator (= l)
#pragma unroll
  for (int n = 0; n < 4; ++n) o_[n] = (f32x4){0.f, 0.f, 0.f, 0.f};

  const int base = li - 4 * g + 15;            // in [3,30]
  int  srcj[4];
  bool cndj[4];
#pragma unroll
  for (int j = 0; j < 4; ++j) {
    srcj[j] = ((base - j) & 15) | (lane & 48);
    cndj[j] = (base - j) < 16;
  }

  // staging regs: kb/vt one chunk per thread (512 chunks); rk band 4 chunks
  // per thread of each half (tid>>8 selects the half's band).
  u16x8 sk, svv, srr[4];
  const int bhalf = tid >> 8;
  const int tid2  = tid & 255;
  auto ISSUE = [&](int itx) {
    const int j0 = itx * 64;
    const int r = tid >> 3, ch = tid & 7;
    sk  = *(const u16x8*)(kbB + (int64_t)(j0 + r) * 512 + ch * 8);
    svv = *(const u16x8*)(vtB + (int64_t)r * 1024 + j0 + ch * 8);
    const int ub = 1024 + j0 - (qt * 128 + bhalf * 64) - 63;   // >= 1
#pragma unroll
    for (int p = 0; p < 4; ++p) {
      const int flat = p * 256 + tid2, r2 = flat >> 3, ch2 = flat & 7;
      int u = ub + r2; u = u < 2047 ? u : 2047;
      srr[p] = *(const u16x8*)(rkB + (int64_t)u * 512 + ch2 * 8);
    }
  };

  ISSUE(0);
  for (int it = 0; it < 16; ++it) {
    __syncthreads();   // prev compute's LDS reads done
    {
      const int r = tid >> 3, ch = tid & 7;
      *(u16x8*)&kbLds[swzIdx(r, ch)] = sk;
      *(u16x8*)&vtLds[swzIdx(r, ch)] = svv;
#pragma unroll
      for (int p = 0; p < 4; ++p) {
        const int flat = p * 256 + tid2, r2 = flat >> 3, ch2 = flat & 7;
        *(u16x8*)&rkLds[bhalf][swzIdx(r2, ch2)] = srr[p];
      }
    }
    __syncthreads();   // tile visible
    if (it < 15) ISSUE(it + 1);   // flies under compute

    // ---- content logits ----
    f32x4 c_[4];
#pragma unroll
    for (int n = 0; n < 4; ++n) c_[n] = (f32x4){0.f, 0.f, 0.f, 0.f};
#pragma unroll
    for (int kc = 0; kc < 2; ++kc) {
      const int chn = kc * 4 + g;
#pragma unroll
      for (int n = 0; n < 4; ++n) {
        bf16x8 bb = *(const bf16x8*)&kbLds[swzIdx(n * 16 + li, chn)];
        c_[n] = __builtin_amdgcn_mfma_f32_16x16x32_bf16(qcf[kc], bb, c_[n], 0, 0, 0);
      }
    }
    // ---- rel band ----
    f32x4 r_[5];
#pragma unroll
    for (int f = 0; f < 5; ++f) r_[f] = (f32x4){0.f, 0.f, 0.f, 0.f};
#pragma unroll
    for (int kc = 0; kc < 2; ++kc) {
      const int chn = kc * 4 + g;
#pragma unroll
      for (int f = 0; f < 5; ++f) {
        const int lr = f * 16 + li + 48 - 16 * wl;
        bf16x8 bb = *(const bf16x8*)&rkLds[th][swzIdx(lr, chn)];
        r_[f] = __builtin_amdgcn_mfma_f32_16x16x32_bf16(qrf[kc], bb, r_[f], 0, 0, 0);
      }
    }
    // ---- band merge: 20 bpermutes + local select ----
    float vsh[5][4];
#pragma unroll
    for (int f = 0; f < 5; ++f)
#pragma unroll
      for (int j = 0; j < 4; ++j)
        vsh[f][j] = __shfl(r_[f][j], srcj[j], 64);
    float sv2[4][4];
#pragma unroll
    for (int n = 0; n < 4; ++n)
#pragma unroll
      for (int j = 0; j < 4; ++j)
        sv2[n][j] = c_[n][j] + (cndj[j] ? vsh[n][j] : vsh[n + 1][j]);

    // ---- online softmax: max-reduce + exact defer-rescale ----
    float tmax[4];
    bool grow = false;
#pragma unroll
    for (int j = 0; j < 4; ++j) {
      float t = fmaxf(fmaxf(sv2[0][j], sv2[1][j]), fmaxf(sv2[2][j], sv2[3][j]));
#pragma unroll
      for (int off = 1; off < 16; off <<= 1) t = fmaxf(t, __shfl_xor(t, off, 64));
      tmax[j] = t;
      grow = grow || (t > m_[j]);
    }
    if (__any(grow)) {
      float al[4];
#pragma unroll
      for (int j = 0; j < 4; ++j) {
        const float nm = fmaxf(m_[j], tmax[j]);
        al[j] = __expf(m_[j] - nm);
        m_[j] = nm;
      }
#pragma unroll
      for (int n = 0; n < 4; ++n)
#pragma unroll
        for (int j = 0; j < 4; ++j) o_[n][j] *= al[j];
#pragma unroll
      for (int j = 0; j < 4; ++j) o4[j] *= al[j];
    }
    u16* pw = pLds[w];
#pragma unroll
    for (int n = 0; n < 4; ++n)
#pragma unroll
      for (int j = 0; j < 4; ++j) {
        const float p = __expf(sv2[n][j] - m_[j]);
        const int rw = g * 4 + j, col = n * 16 + li;
        pw[(rw << 6) + ((((col >> 3) ^ (rw & 7)) & 7) << 3) + (col & 7)] = f2bf(p);
      }

    // ---- PV (+ ones column accumulates l) ----
#pragma unroll
    for (int kc = 0; kc < 2; ++kc) {
      const int chn = kc * 4 + g;
      bf16x8 pa = *(const bf16x8*)&pw[swzIdx(li, chn)];
#pragma unroll
      for (int n = 0; n < 4; ++n) {
        bf16x8 vb = *(const bf16x8*)&vtLds[swzIdx(n * 16 + li, chn)];
        o_[n] = __builtin_amdgcn_mfma_f32_16x16x32_bf16(pa, vb, o_[n], 0, 0, 0);
      }
      o4 = __builtin_amdgcn_mfma_f32_16x16x32_bf16(pa, ones, o4, 0, 0, 0);
    }
  }

  float inv[4];
#pragma unroll
  for (int j = 0; j < 4; ++j) inv[j] = 1.f / o4[j];
  u16* obB = ob + (int64_t)b * 524288 + (int64_t)(t0 + wl * 16) * 512 + h * 64;
#pragma unroll
  for (int n = 0; n < 4; ++n)
#pragma unroll
    for (int j = 0; j < 4; ++j)
      obB[(int64_t)(g * 4 + j) * 512 + n * 16 + li] = f2bf(o_[n][j] * inv[j]);
}

enum { EPI_BF16 = 0, EPI_BF16_RELU = 1, EPI_F32 = 2, EPI_QKV = 6 };

// C[m,n] = sum_k A[m,k] * Bt[n,k].  Tile 128 x (NW*32).  gld_lds staging,
// double-buffered 2-phase.
template <int EPI, int NW>
__global__ __launch_bounds__(256) void gemm_bt(
    const u16* __restrict__ A, int64_t zA, int lda,
    const u16* __restrict__ Bt, int64_t zB, int ldb,
    char* __restrict__ Cb, int64_t zCbytes, int ldc,
    const float* __restrict__ bias1, int zbias,
    int M, int N, int K)
{
  __shared__ __align__(16) u16 As[2][128 * BK];
  __shared__ __align__(16) u16 Bs[2][NW * 32 * BK];

  const int z = blockIdx.z;
  A  += (int64_t)z * zA;
  Bt += (int64_t)z * zB;
  Cb += (int64_t)z * zCbytes;

  const int m0 = blockIdx.y * 128;
  const int n0 = blockIdx.x * (NW * 32);

  const int tid  = threadIdx.x;
  const int lane = tid & 63;
  const int wid  = tid >> 6;
  const int wm = (wid >> 1) * 64;
  const int wn = (wid & 1) * (NW * 16);
  const int fr = lane & 15;
  const int fk = (lane >> 4) * 8;

  f32x4 acc[4][NW];
#pragma unroll
  for (int m = 0; m < 4; ++m)
#pragma unroll
    for (int n = 0; n < NW; ++n) acc[m][n] = (f32x4){0.f, 0.f, 0.f, 0.f};

  const int nsteps = K >> 6;
  auto STAGE = [&](int step, int buf) {
    const int kt = step * BK;
#pragma unroll
    for (int it = 0; it < 4; ++it) {
      const int off = (it * 256 + tid) * 8;
      const int r = off >> 6, c = off & (BK - 1);
      int gr = m0 + r; if (gr > M - 1) gr = M - 1;
      gld16(A + (int64_t)gr * lda + kt + c, &As[buf][off]);
    }
#pragma unroll
    for (int it = 0; it < NW; ++it) {
      const int off = (it * 256 + tid) * 8;
      const int r = off >> 6, c = off & (BK - 1);
      int gr = n0 + r; if (gr > N - 1) gr = N - 1;
      gld16(Bt + (int64_t)gr * ldb + kt + c, &Bs[buf][off]);
    }
  };

  STAGE(0, 0);
  for (int s = 0; s < nsteps; ++s) {
    const int cur = s & 1;
    __syncthreads();
    if (s + 1 < nsteps) STAGE(s + 1, cur ^ 1);

#pragma unroll
    for (int kk = 0; kk < BK; kk += 32) {
      bf16x8 af[4], bfv[NW];
#pragma unroll
      for (int m = 0; m < 4; ++m)
        af[m] = *(const bf16x8*)&As[cur][(wm + m * 16 + fr) * BK + kk + fk];
#pragma unroll
      for (int n = 0; n < NW; ++n)
        bfv[n] = *(const bf16x8*)&Bs[cur][(wn + n * 16 + fr) * BK + kk + fk];
#pragma unroll
      for (int m = 0; m < 4; ++m)
#pragma unroll
        for (int n = 0; n < NW; ++n)
          acc[m][n] = __builtin_amdgcn_mfma_f32_16x16x32_bf16(af[m], bfv[n], acc[m][n], 0, 0, 0);
    }
  }

  const int r0 = m0 + wm + (lane >> 4) * 4;
  const int c0 = n0 + wn + fr;
#pragma unroll
  for (int m = 0; m < 4; ++m) {
#pragma unroll
    for (int n = 0; n < NW; ++n) {
      const int col = c0 + n * 16;
      if (col >= N) continue;
      float b1v = 0.f;
      if (EPI == EPI_BF16 || EPI == EPI_BF16_RELU) {
        if (bias1) b1v = bias1[z * zbias + col];
      }
#pragma unroll
      for (int j = 0; j < 4; ++j) {
        const int row = r0 + m * 16 + j;
        if (row >= M) continue;
        const float v = acc[m][n][j];
        if (EPI == EPI_BF16) {
          ((u16*)Cb)[(int64_t)row * ldc + col] = f2bf(v + b1v);
        } else if (EPI == EPI_BF16_RELU) {
          float t = v + b1v; t = t > 0.f ? t : 0.f;
          ((u16*)Cb)[(int64_t)row * ldc + col] = f2bf(t);
        } else if (EPI == EPI_F32) {
          ((float*)Cb)[(int64_t)row * ldc + col] = v;
        }
      }
    }
  }
}

// Merged QKV + rk projection.  896 blocks: [0,768) QKV (N=1536 over
// WqT|WkT|WvT, M=4096), [768,896) rk = pe@WrT (M=2048, N=512).  NW=2.
__global__ __launch_bounds__(256) void gemm_qkv_rk(
    const u16* __restrict__ xb, const u16* __restrict__ pe,
    const u16* __restrict__ WqkvT, const u16* __restrict__ WrT,
    char* __restrict__ qcBase, u16* __restrict__ rkOut,
    const float* __restrict__ biasAll)
{
  __shared__ __align__(16) u16 As[2][128 * BK];
  __shared__ __align__(16) u16 Bs[2][64 * BK];

  const bool isRk = blockIdx.x >= 768;
  const int bidl = isRk ? (blockIdx.x - 768) : blockIdx.x;
  const int m0 = isRk ? (bidl >> 3) * 128 : (bidl / 24) * 128;
  const int n0 = isRk ? (bidl & 7) * 64   : (bidl % 24) * 64;
  const u16* A  = isRk ? pe   : xb;
  const u16* Bt = isRk ? WrT  : WqkvT;
  const int  N  = isRk ? 512  : 1536;

  const int tid  = threadIdx.x;
  const int lane = tid & 63;
  const int wid  = tid >> 6;
  const int wm = (wid >> 1) * 64;
  const int wn = (wid & 1) * 32;
  const int fr = lane & 15;
  const int fk = (lane >> 4) * 8;

  f32x4 acc[4][2];
#pragma unroll
  for (int m = 0; m < 4; ++m)
#pragma unroll
    for (int n = 0; n < 2; ++n) acc[m][n] = (f32x4){0.f, 0.f, 0.f, 0.f};

  auto STAGE = [&](int step, int buf) {
    const int kt = step * BK;
#pragma unroll
    for (int it = 0; it < 4; ++it) {
      const int off = (it * 256 + tid) * 8;
      const int r = off >> 6, c = off & (BK - 1);
      gld16(A + (int64_t)(m0 + r) * 512 + kt + c, &As[buf][off]);
    }
#pragma unroll
    for (int it = 0; it < 2; ++it) {
      const int off = (it * 256 + tid) * 8;
      const int r = off >> 6, c = off & (BK - 1);
      gld16(Bt + (int64_t)(n0 + r) * 512 + kt + c, &Bs[buf][off]);
    }
  };

  STAGE(0, 0);
  for (int s = 0; s < 8; ++s) {      // K = 512
    const int cur = s & 1;
    __syncthreads();
    if (s + 1 < 8) STAGE(s + 1, cur ^ 1);

#pragma unroll
    for (int kk = 0; kk < BK; kk += 32) {
      bf16x8 af[4], bfv[2];
#pragma unroll
      for (int m = 0; m < 4; ++m)
        af[m] = *(const bf16x8*)&As[cur][(wm + m * 16 + fr) * BK + kk + fk];
#pragma unroll
      for (int n = 0; n < 2; ++n)
        bfv[n] = *(const bf16x8*)&Bs[cur][(wn + n * 16 + fr) * BK + kk + fk];
#pragma unroll
      for (int m = 0; m < 4; ++m)
#pragma unroll
        for (int n = 0; n < 2; ++n)
          acc[m][n] = __builtin_amdgcn_mfma_f32_16x16x32_bf16(af[m], bfv[n], acc[m][n], 0, 0, 0);
    }
  }

  const int r0 = m0 + wm + (lane >> 4) * 4;
  const int c0 = n0 + wn + fr;
#pragma unroll
  for (int m = 0; m < 4; ++m) {
#pragma unroll
    for (int n = 0; n < 2; ++n) {
      const int col = c0 + n * 16;
      (void)N;
#pragma unroll
      for (int j = 0; j < 4; ++j) {
        const int row = r0 + m * 16 + j;
        const float v = acc[m][n][j];
        if (isRk) {
          rkOut[(int64_t)row * 512 + col] = f2bf(v);
        } else {
          const int which = col >> 9, cc = col & 511;
          const int slot = (which == 0) ? 0 : which + 1;   // 0:qc 2:kb 3:vb
          u16* dst = (u16*)qcBase + (int64_t)slot * 2097152
                   + (int64_t)row * 512 + cc;
          *dst = f2bf(v + biasAll[slot * 512 + cc]);
          if (which == 0)                                   // slot 1: qr
            dst[2097152] = f2bf(v + biasAll[512 + cc]);
        }
      }
    }
  }
}

// ---------------------------------------------------------------------------
// ALL preprocessing in one dispatch (9474 blocks).
// ---------------------------------------------------------------------------
__global__ __launch_bounds__(256) void prep_all(
    const float* __restrict__ x,
    const float* __restrict__ Wq, const float* __restrict__ Wk,
    const float* __restrict__ Wv, const float* __restrict__ Wo,
    const float* __restrict__ Wr, const float* __restrict__ W1,
    const float* __restrict__ W2,
    const float* __restrict__ bq, const float* __restrict__ cb,
    const float* __restrict__ rb, const float* __restrict__ bk,
    const float* __restrict__ bv, char* __restrict__ wsb)
{
  __shared__ float t[32][33];
  const int bid = blockIdx.x;
  const int tid = threadIdx.x;
  if (bid < 4096) {                       // pe
    u16* pe = (u16*)(wsb + 20480);
    int idx = bid * 256 + tid;
    int i = idx >> 9, j = idx & 511, jf = j & 255;
    float inv = __expf(-(float)jf * (2.0f / 512.0f) * 9.210340371976184f);
    float arg = (float)(i - 1024) * inv;
    pe[idx] = f2bf((j < 256) ? __sinf(arg) : __cosf(arg));
  } else if (bid < 6144) {                // convert x
    u16* xb = (u16*)(wsb + 8933376);
    int idx = (bid - 4096) * 256 + tid;
    f32x4 v = ((const f32x4*)x)[idx];
    u16x4 o;
    o[0] = f2bf(v[0]); o[1] = f2bf(v[1]); o[2] = f2bf(v[2]); o[3] = f2bf(v[3]);
    ((u16x4*)xb)[idx] = o;
  } else if (bid < 6146) {                // biases (bqc|bqr|bkv contiguous)
    int i = (bid - 6144) * 256 + tid;
    float* bqc = (float*)wsb;
    if (i < 512) {
      bqc[i]        = bq[i] + cb[i];
      bqc[512 + i]  = bq[i] + rb[i];
      bqc[1024 + i] = bk[i];
      bqc[1536 + i] = bv[i];
    }
  } else {                                // transposes
    const int tl0 = bid - 6146;
    const float* src; u16* dst;
    int ldi, ldo, bx, by;
    if (tl0 < 1280) {
      const int wsel = tl0 >> 8, tl = tl0 & 255;
      bx = tl & 15; by = tl >> 4; ldi = 512; ldo = 512;
      src = (wsel == 0) ? Wq : (wsel == 1) ? Wk : (wsel == 2) ? Wv
          : (wsel == 3) ? Wo : Wr;
      dst = (u16*)(wsb + 2117632 + (int64_t)wsel * 524288);
    } else if (tl0 < 2304) {
      const int tl = tl0 - 1280;
      bx = tl & 63; by = tl >> 6; ldi = 2048; ldo = 512;
      src = W1; dst = (u16*)(wsb + 4739072);
    } else {
      const int tl = tl0 - 2304;
      bx = tl & 15; by = tl >> 4; ldi = 512; ldo = 2048;
      src = W2; dst = (u16*)(wsb + 6836224);
    }
    const int xx = tid & 31, yy = tid >> 5;   // 32 x 8
    const int r0 = by * 32, c0 = bx * 32;
#pragma unroll
    for (int i = 0; i < 32; i += 8)
      t[yy + i][xx] = src[(int64_t)(r0 + yy + i) * ldi + c0 + xx];
    __syncthreads();
#pragma unroll
    for (int i = 0; i < 32; i += 8)
      dst[(int64_t)(c0 + yy + i) * ldo + r0 + xx] = f2bf(t[xx][yy + i]);
  }
}

// v (b,l,h,dh) bf16 -> vt (b,h,dh,l) bf16;  z = b*8+h
__global__ void transpose_v_kernel(const u16* __restrict__ v, u16* __restrict__ vt) {
  __shared__ u16 t[32][33];
  int z = blockIdx.z;
  const u16* in = v + (int64_t)(z >> 3) * 524288 + (z & 7) * 64;
  u16* out = vt + (int64_t)z * 65536;
  int c0 = blockIdx.x * 32, r0 = blockIdx.y * 32;
  int x = threadIdx.x, y = threadIdx.y;
#pragma unroll
  for (int i = 0; i < 32; i += 8)
    t[y + i][x] = in[(int64_t)(r0 + y + i) * 512 + c0 + x];
  __syncthreads();
#pragma unroll
  for (int i = 0; i < 32; i += 8)
    out[(int64_t)(c0 + y + i) * 1024 + r0 + x] = t[x][y + i];
}

// LN over val = 2*(X1 + X2 + bias).  one wave/row, 4 rows/block, grid(1024).
template <int OUT_F32>
__global__ void layernorm_sum2_kernel(
    const float* __restrict__ X1, const float* __restrict__ X2,
    const float* __restrict__ bias,
    const float* __restrict__ sc, const float* __restrict__ bi,
    void* __restrict__ outv) {
  const int row = blockIdx.x * 4 + (threadIdx.x >> 6);
  const int lane = threadIdx.x & 63;
  const int64_t ro = (int64_t)row * 512;
  f32x4 a1 = ((const f32x4*)(X1 + ro))[lane];
  f32x4 a2 = ((const f32x4*)(X1 + ro))[lane + 64];
  f32x4 b1 = ((const f32x4*)(X2 + ro))[lane];
  f32x4 b2 = ((const f32x4*)(X2 + ro))[lane + 64];
  f32x4 c1 = ((const f32x4*)bias)[lane];
  f32x4 c2 = ((const f32x4*)bias)[lane + 64];
  f32x4 a, b;
#pragma unroll
  for (int e = 0; e < 4; ++e) {
    a[e] = 2.f * (a1[e] + b1[e] + c1[e]);
    b[e] = 2.f * (a2[e] + b2[e] + c2[e]);
  }
  float s = 0.f, q = 0.f;
#pragma unroll
  for (int e = 0; e < 4; ++e) { s += a[e] + b[e]; q += a[e]*a[e] + b[e]*b[e]; }
#pragma unroll
  for (int o = 32; o; o >>= 1) { s += __shfl_xor(s, o, 64); q += __shfl_xor(q, o, 64); }
  const float mu = s * (1.f / 512.f);
  const float var = q * (1.f / 512.f) - mu * mu;
  const float r = rsqrtf(var + 1e-6f);
  const int cc1 = lane * 4, cc2 = (lane + 64) * 4;
  f32x4 s1 = ((const f32x4*)sc)[lane], s2 = ((const f32x4*)sc)[lane + 64];
  f32x4 g1 = ((const f32x4*)bi)[lane], g2 = ((const f32x4*)bi)[lane + 64];
  if (OUT_F32) {
    float* out = (float*)outv;
    f32x4 o1, o2;
#pragma unroll
    for (int e = 0; e < 4; ++e) {
      o1[e] = (a[e] - mu) * r * s1[e] + g1[e];
      o2[e] = (b[e] - mu) * r * s2[e] + g2[e];
    }
    *(f32x4*)&out[ro + cc1] = o1;
    *(f32x4*)&out[ro + cc2] = o2;
  } else {
    u16* out = (u16*)outv;
    u16x4 o1, o2;
#pragma unroll
    for (int e = 0; e < 4; ++e) {
      o1[e] = f2bf((a[e] - mu) * r * s1[e] + g1[e]);
      o2[e] = f2bf((b[e] - mu) * r * s2[e] + g2[e]);
    }
    *(u16x4*)&out[ro + cc1] = o1;
    *(u16x4*)&out[ro + cc2] = o2;
  }
}

// ---------------------------------------------------------------------------
extern "C" void kernel_launch(void* const* d_in, const int* in_sizes, int n_in,
                              void* d_out, int out_size, void* d_ws, size_t ws_size,
                              hipStream_t stream) {
  const float* x    = (const float*)d_in[0];
  const float* Wq   = (const float*)d_in[1];
  const float* bq   = (const float*)d_in[2];
  const float* Wk   = (const float*)d_in[3];
  const float* bk   = (const float*)d_in[4];
  const float* Wv   = (const float*)d_in[5];
  const float* bv   = (const float*)d_in[6];
  const float* cb   = (const float*)d_in[7];
  const float* rb   = (const float*)d_in[8];
  const float* Wr   = (const float*)d_in[9];
  const float* Wo   = (const float*)d_in[10];
  const float* bo   = (const float*)d_in[11];
  const float* ln1s = (const float*)d_in[12];
  const float* ln1b = (const float*)d_in[13];
  const float* W1   = (const float*)d_in[14];
  const float* b1   = (const float*)d_in[15];
  const float* W2   = (const float*)d_in[16];
  const float* b2   = (const float*)d_in[17];
  const float* ln2s = (const float*)d_in[18];
  const float* ln2b = (const float*)d_in[19];
  (void)in_sizes; (void)n_in; (void)out_size; (void)ws_size;

  char* ws = (char*)d_ws;
  float* bqc = (float*)(ws + 0);          // bqc|bqr|bkv contiguous (2048 f32)
  u16* pe  = (u16*)(ws + 20480);          // 2048x512 bf16
  u16* WqT = (u16*)(ws + 2117632);        // Wq|Wk|Wv T contiguous (1536x512)
  u16* WoT = (u16*)(ws + 3690496);
  u16* WrT = (u16*)(ws + 4214784);
  u16* W1T = (u16*)(ws + 4739072);        // 2048x512
  u16* W2T = (u16*)(ws + 6836224);        // 512x2048
  u16* xb  = (u16*)(ws + 8933376);        // 4096x512 bf16
  u16* qc  = (u16*)(ws + 13127680);       // qc|qr|kb|vb each +2097152 u16
  u16* kb  = (u16*)(ws + 21516288);
  u16* vb  = (u16*)(ws + 25710592);
  u16* vt  = (u16*)(ws + 29904896);       // (b,h,dh,l)
  u16* rk  = (u16*)(ws + 34099200);       // 2048x512
  u16* ob  = (u16*)(ws + 36196352);       // 4096x512 (attn out)
  char* scratch = ws + 40390656;
  float* pA  = (float*)scratch;                   // 4096x512 fp32
  float* pB  = (float*)(ws + 13127680);           // qc region (dead post-attn)
  u16*   ln1 = (u16*)(scratch + 8388608);         // 4096x512 bf16
  u16*   ffn1= (u16*)(scratch + 12582912);        // 4096x2048 bf16
  const int64_t zPart = (int64_t)((char*)pB - (char*)pA);

  const dim3 blk(256), tb(32, 8);

  prep_all<<<dim3(9474), blk, 0, stream>>>(x, Wq, Wk, Wv, Wo, Wr, W1, W2,
                                           bq, cb, rb, bk, bv, ws);

  // fused q/qr/k/v projection + rk projection in one dispatch
  gemm_qkv_rk<<<dim3(896), blk, 0, stream>>>(xb, pe, WqT, WrT,
                                             (char*)qc, rk, bqc);
  transpose_v_kernel<<<dim3(2, 32, 32), tb, 0, stream>>>(vb, vt);

  // fused attention (256 blocks x 512 threads; XCD = bid&7)
  fused_attn_kernel<<<dim3(256), dim3(512), 0, stream>>>(
      qc, qc + 2097152, kb, vt, rk, ob);

  // o@Wo, K-split z=2 -> partials; LN1 folds +bo, x2, sum
  gemm_bt<EPI_F32, 2><<<dim3(8, 32, 2), blk, 0, stream>>>(
      ob, 256, 512, WoT, 256, 512, (char*)pA, zPart, 512, nullptr, 0,
      4096, 512, 256);
  layernorm_sum2_kernel<0><<<dim3(1024), blk, 0, stream>>>(
      pA, pB, bo, ln1s, ln1b, ln1);
  // FFN
  gemm_bt<EPI_BF16_RELU, 4><<<dim3(16, 32, 1), blk, 0, stream>>>(
      ln1, 0, 512, W1T, 0, 512, (char*)ffn1, 0, 2048, b1, 0, 4096, 2048, 512);
  gemm_bt<EPI_F32, 2><<<dim3(8, 32, 2), blk, 0, stream>>>(
      ffn1, 1024, 2048, W2T, 1024, 2048, (char*)pA, zPart, 512, nullptr, 0,
      4096, 512, 1024);
  layernorm_sum2_kernel<1><<<dim3(1024), blk, 0, stream>>>(
      pA, pB, b2, ln2s, ln2b, d_out);
}